// Round 18
// baseline (198.795 us; speedup 1.0000x reference)
//
#include <hip/hip_runtime.h>
#include <hip/hip_bf16.h>
#include <stdint.h>

// out = x + x * [ (Wq Wk^T) * (x^T x) * (Wv P) ]  ==  x @ (I + N),  N = U G W2
// Final GEMM: A via LDS prefetch-3 (24 KB), B (L2-resident Ntb) read DIRECTLY
// from global into registers — per-wave vmcnt in-order retirement makes the
// compiler's own B-reg waits subsume the A-stage protocol (no manual in-loop
// vmcnt). Gram: 128^2 pipeline, bf16 split-K partials + fused mirror.

#define BATCH 4
#define SEQ   4096
#define DIM   1024

#define TRI_SLICE 589824l       // 36 tiles * 128*128 elements per gram slice

typedef __bf16 bf16x8 __attribute__((ext_vector_type(8)));
typedef float f32x4 __attribute__((ext_vector_type(4)));

static __device__ __forceinline__ unsigned short f2bf(float f) {
    unsigned int u = __builtin_bit_cast(unsigned int, f);
    u += 0x7fff + ((u >> 16) & 1);              // RNE
    return (unsigned short)(u >> 16);
}
static __device__ __forceinline__ float bf2f(unsigned short h) {
    unsigned int u = (unsigned int)h << 16;
    return __builtin_bit_cast(float, u);
}

// ---------------------------------------------------------------------------
// Final GEMM: C = A @ Bt^T (fp32 out). Tile 128M x 256N, BK=32, 256 thr =
// 4 waves (2M x 2N), per-wave 64x128.
//  A: LDS [3][128][32] (24 KB), global_load_lds prefetch-3, swizzle
//     S(row)=(row>>1)&3 (conflicts measured 0).
//  B: 8 x dwordx4 per tile straight from global (Ntb is L2-resident);
//     compiler-inserted per-wave waits + in-order vmcnt retirement subsume
//     the A-stage completion -> no manual in-loop vmcnt.
// Grid: (N/256, M/128, BATCH); flattened nwg % 8 == 0. K/32 >= 3.
// ---------------------------------------------------------------------------
__global__ __launch_bounds__(256, 2)
void gemm_fin(const unsigned short* __restrict__ Ag,
              const unsigned short* __restrict__ Btg,
              float* __restrict__ Cg,
              int K, int lda, int ldbt, int ldc,
              long sA, long sBt, long sC)
{
    __shared__ unsigned short As[3][128][32];

    const int gx = gridDim.x, gy = gridDim.y;
    const int nwg = gx * gy * gridDim.z;
    int id = blockIdx.x + gx * (blockIdx.y + gy * blockIdx.z);
    id = (id & 7) * (nwg >> 3) + (id >> 3);

    const int bx = id % gx;
    const int rest = id / gx;
    const int by = rest % gy;
    const int b = rest / gy;
    const long i0 = (long)by * 128;
    const long j0 = (long)bx * 256;

    const unsigned short* A  = Ag  + (long)b * sA;
    const unsigned short* Bt = Btg + (long)b * sBt;

    const int tid  = threadIdx.x;
    const int lane = tid & 63;
    const int w    = tid >> 6;          // wave 0..3
    const int wr   = w >> 1, wc = w & 1;
    const int srow = lane >> 2;         // 0..15 staging row within 16-row group
    const int sch  = lane & 3;          // staging 16B chunk 0..3
    const int fr   = lane & 15;
    const int kg   = lane >> 4;         // 0..3
    const int ch   = (kg ^ ((fr >> 1) & 3)) * 8;   // swizzled A read chunk

    // B row pointers (k-contiguous rows of Ntb), one per n-fragment
    const unsigned short* Brow[8];
#pragma unroll
    for (int n = 0; n < 8; ++n)
        Brow[n] = Bt + (j0 + wc * 128 + n * 16 + fr) * (long)ldbt + kg * 8;

    f32x4 acc[4][8] = {};
    const int nt = K / 32;

    auto stageA = [&](int t, int buf) {
        const long kk = (long)t * 32;
        const long scoff = (long)((sch ^ ((srow >> 1) & 3)) * 8); // pre-swz src
#pragma unroll
        for (int inst = 0; inst < 2; ++inst) {
            const int row = inst * 64 + w * 16 + srow;
            const unsigned short* src = A + (i0 + row) * lda + kk + scoff;
            __builtin_amdgcn_global_load_lds(
                (const __attribute__((address_space(1))) void*)src,
                (__attribute__((address_space(3))) void*)&As[buf][inst * 64 + w * 16][0],
                16, 0, 0);
        }
    };

    // prologue: A tiles 0..2 in flight; wait own A(0) (4 newer allowed), sync
    stageA(0, 0);
    stageA(1, 1);
    stageA(2, 2);
    asm volatile("s_waitcnt vmcnt(4)" ::: "memory");
    __builtin_amdgcn_s_barrier();
    asm volatile("" ::: "memory");

    for (int t = 0; t < nt; ++t) {
        const int buf = t % 3;
        const long kk = (long)t * 32;

        // B fragments for this tile: plain global loads (compiler-managed wait)
        bf16x8 bv[8];
#pragma unroll
        for (int n = 0; n < 8; ++n)
            bv[n] = *(const bf16x8*)&Brow[n][kk];

        // A fragments from LDS (4 x ds_read_b128)
        bf16x8 af[4];
#pragma unroll
        for (int m = 0; m < 4; ++m)
            af[m] = *(const bf16x8*)&As[buf][wr * 64 + m * 16 + fr][ch];

        asm volatile("s_waitcnt lgkmcnt(0)" ::: "memory");
        __builtin_amdgcn_sched_barrier(0);
        __builtin_amdgcn_s_barrier();       // all waves done reading A buf
        asm volatile("" ::: "memory");

        if (t + 3 < nt) stageA(t + 3, buf); // overwrite freed buffer
        __builtin_amdgcn_sched_barrier(0);

        __builtin_amdgcn_s_setprio(1);
#pragma unroll
        for (int m = 0; m < 4; ++m)
#pragma unroll
            for (int n = 0; n < 8; ++n)
                acc[m][n] = __builtin_amdgcn_mfma_f32_16x16x32_bf16(
                    af[m], bv[n], acc[m][n], 0, 0, 0);
        __builtin_amdgcn_s_setprio(0);

        __builtin_amdgcn_s_barrier();       // bottom: next iter's reads safe
        asm volatile("" ::: "memory");
    }

    // epilogue: C/D layout col = lane&15, row = (lane>>4)*4 + q
    float* C32 = Cg + (long)b * sC;
#pragma unroll
    for (int m = 0; m < 4; ++m) {
        const long rbase = i0 + wr * 64 + m * 16 + kg * 4;
#pragma unroll
        for (int n = 0; n < 8; ++n) {
            const long col = j0 + wc * 128 + n * 16 + fr;
#pragma unroll
            for (int q = 0; q < 4; ++q)
                C32[(rbase + q) * ldc + col] = acc[m][n][q];
        }
    }
}

// ---------------------------------------------------------------------------
// 128 x BN deep-pipelined bf16 MFMA GEMM (proven rounds 9-17) — gram + chain.
//  OUTMODE: 0 fp32 out; 1 bf16 out (+ADD_I); 3 TRI compact BF16 partial.
// ---------------------------------------------------------------------------
template<int OUTMODE, int BN, bool TRI, bool ADD_I>
__global__ __launch_bounds__(256)
void gemm_db(const unsigned short* __restrict__ Ag,
             const unsigned short* __restrict__ Btg,
             void* __restrict__ Cg,
             int K, int zdiv, int lda, int ldbt, int ldc,
             long sA, long sBt, long sC)
{
    constexpr int NF = BN / 32;             // B fragments per wave (2 or 4)
    __shared__ unsigned short As[2][128][64];
    __shared__ unsigned short Bs[2][BN][64];

    const int gx = gridDim.x, gy = gridDim.y;
    const int nwg = gx * gy * gridDim.z;
    int id = blockIdx.x + gx * (blockIdx.y + gy * blockIdx.z);
    id = (id & 7) * (nwg >> 3) + (id >> 3);

    int z, tlin = 0;
    long i0, j0;
    if (TRI) {
        z = id / 36;
        tlin = id % 36;
        int t = tlin, ti = 0;
        while (t > ti) { t -= ti + 1; ++ti; }
        i0 = (long)ti * 128;
        j0 = (long)t * 128;
    } else {
        const int bx = id % gx;
        const int rest = id / gx;
        const int by = rest % gy;
        z = rest / gy;
        i0 = (long)by * 128;
        j0 = (long)bx * BN;
    }
    const int b = z / zdiv;
    const long koff = (long)(z % zdiv) * K;

    const unsigned short* A  = Ag  + (long)b * sA  + koff;
    const unsigned short* Bt = Btg + (long)b * sBt + koff;

    const int tid  = threadIdx.x;
    const int lane = tid & 63;
    const int w    = tid >> 6;          // wave 0..3
    const int wr   = w >> 1, wc = w & 1;
    const int lrow = lane >> 3;         // 0..7
    const int lcol = lane & 7;          // 0..7 (16B granule)
    const int fr   = lane & 15;
    const int kg   = lane >> 4;         // 0..3
    const int scol = (lcol ^ lrow) * 8; // pre-swizzled global source chunk

    f32x4 acc[4][NF] = {};

    const int nt = K / 64;              // >= 2 always

    auto stage = [&](int t, int buf) {
        const long kk = (long)t * 64;
#pragma unroll
        for (int inst = 0; inst < 4; ++inst) {
            const int row = w * 32 + inst * 8;
            const unsigned short* srcA = A + (i0 + row + lrow) * lda + kk + scol;
            __builtin_amdgcn_global_load_lds(
                (const __attribute__((address_space(1))) void*)srcA,
                (__attribute__((address_space(3))) void*)&As[buf][row][0], 16, 0, 0);
        }
#pragma unroll
        for (int inst = 0; inst < NF; ++inst) {
            const int row = w * (8 * NF) + inst * 8;
            const unsigned short* srcB = Bt + (j0 + row + lrow) * ldbt + kk + scol;
            __builtin_amdgcn_global_load_lds(
                (const __attribute__((address_space(1))) void*)srcB,
                (__attribute__((address_space(3))) void*)&Bs[buf][row][0], 16, 0, 0);
        }
    };

    stage(0, 0);
    stage(1, 1);

    for (int t = 0; t < nt; ++t) {
        const int buf = t & 1;
        if (t < nt - 1) {
            if constexpr (BN == 128)
                asm volatile("s_waitcnt vmcnt(8)" ::: "memory");
            else
                asm volatile("s_waitcnt vmcnt(6)" ::: "memory");
        } else {
            asm volatile("s_waitcnt vmcnt(0)" ::: "memory");
        }
        __builtin_amdgcn_s_barrier();
        asm volatile("" ::: "memory");

        bf16x8 af0[4], bf0[NF], af1[4], bf1[NF];
        const int ch0 = (kg ^ (fr & 7)) * 8;
        const int ch1 = ((4 + kg) ^ (fr & 7)) * 8;
#pragma unroll
        for (int m = 0; m < 4; ++m)
            af0[m] = *(const bf16x8*)&As[buf][wr * 64 + m * 16 + fr][ch0];
#pragma unroll
        for (int n = 0; n < NF; ++n)
            bf0[n] = *(const bf16x8*)&Bs[buf][wc * (BN / 2) + n * 16 + fr][ch0];
#pragma unroll
        for (int m = 0; m < 4; ++m)
            af1[m] = *(const bf16x8*)&As[buf][wr * 64 + m * 16 + fr][ch1];
#pragma unroll
        for (int n = 0; n < NF; ++n)
            bf1[n] = *(const bf16x8*)&Bs[buf][wc * (BN / 2) + n * 16 + fr][ch1];

        __builtin_amdgcn_s_setprio(1);
#pragma unroll
        for (int m = 0; m < 4; ++m)
#pragma unroll
            for (int n = 0; n < NF; ++n)
                acc[m][n] = __builtin_amdgcn_mfma_f32_16x16x32_bf16(
                    af0[m], bf0[n], acc[m][n], 0, 0, 0);
        __builtin_amdgcn_s_setprio(0);

        asm volatile("s_waitcnt lgkmcnt(0)" ::: "memory");
        __builtin_amdgcn_sched_barrier(0);
        __builtin_amdgcn_s_barrier();
        asm volatile("" ::: "memory");

        if (t + 2 < nt) stage(t + 2, buf);
        __builtin_amdgcn_sched_barrier(0);

        __builtin_amdgcn_s_setprio(1);
#pragma unroll
        for (int m = 0; m < 4; ++m)
#pragma unroll
            for (int n = 0; n < NF; ++n)
                acc[m][n] = __builtin_amdgcn_mfma_f32_16x16x32_bf16(
                    af1[m], bf1[n], acc[m][n], 0, 0, 0);
        __builtin_amdgcn_s_setprio(0);
    }

    if (OUTMODE == 3) {
        unsigned short* Cp = (unsigned short*)Cg + (long)z * TRI_SLICE
                           + (long)tlin * 16384;
#pragma unroll
        for (int m = 0; m < 4; ++m) {
            const int lrb = wr * 64 + m * 16 + kg * 4;
#pragma unroll
            for (int n = 0; n < NF; ++n) {
                const int lc = wc * (BN / 2) + n * 16 + fr;
#pragma unroll
                for (int q = 0; q < 4; ++q)
                    Cp[(lrb + q) * 128 + lc] = f2bf(acc[m][n][q]);
            }
        }
        return;
    }

    unsigned short* C16 = (OUTMODE == 1) ? ((unsigned short*)Cg + (long)b * sC) : nullptr;
    float*          C32 = (OUTMODE == 0) ? ((float*)Cg + (long)b * sC) : nullptr;
#pragma unroll
    for (int m = 0; m < 4; ++m) {
        const long rbase = i0 + wr * 64 + m * 16 + kg * 4;
#pragma unroll
        for (int n = 0; n < NF; ++n) {
            const long col = j0 + wc * (BN / 2) + n * 16 + fr;
#pragma unroll
            for (int q = 0; q < 4; ++q) {
                const long r = rbase + q;
                float v = acc[m][n][q];
                if (ADD_I && r == col) v += 1.0f;
                if (OUTMODE == 1) C16[r * ldc + col] = f2bf(v);
                else              C32[r * ldc + col] = v;
            }
        }
    }
}

// ---------------------------------------------------------------------------
// Reduce gram split-K BF16 compact partials -> bf16 G (lower tiles), AND
// write the strict-upper mirror (transposed strip via LDS).
// ---------------------------------------------------------------------------
__global__ __launch_bounds__(256)
void reduce_cast_tri(const unsigned short* __restrict__ part,
                     unsigned short* __restrict__ outG, int split)
{
    __shared__ unsigned short s[8][132];
    const long DD = (long)DIM * DIM;
    int id = blockIdx.x * 256 + threadIdx.x;
    const int b  = id / 147456;          // 36*128*32
    int rem      = id % 147456;
    const int tlin = rem / 4096;
    const int rr = rem % 4096;
    const int r  = rr >> 5;
    const int c4 = rr & 31;
    int t = tlin, ti = 0;
    while (t > ti) { t -= ti + 1; ++ti; }
    const long off = (long)tlin * 16384 + r * 128 + c4 * 4;

    float4 sum = make_float4(0.f, 0.f, 0.f, 0.f);
    for (int sp = 0; sp < split; ++sp) {
        ushort4 v = *(const ushort4*)&part[(long)(b * split + sp) * TRI_SLICE + off];
        sum.x += bf2f(v.x); sum.y += bf2f(v.y); sum.z += bf2f(v.z); sum.w += bf2f(v.w);
    }
    ushort4 o;
    o.x = f2bf(sum.x); o.y = f2bf(sum.y); o.z = f2bf(sum.z); o.w = f2bf(sum.w);
    *(ushort4*)&outG[b * DD + ((long)ti * 128 + r) * DIM + (long)t * 128 + c4 * 4] = o;

    if (t == ti) return;                 // diagonal tile: already complete

    const int rl = r & 7;
    s[rl][c4 * 4 + 0] = o.x; s[rl][c4 * 4 + 1] = o.y;
    s[rl][c4 * 4 + 2] = o.z; s[rl][c4 * 4 + 3] = o.w;
    __syncthreads();

    const int r0 = r & ~7;
    const int co = threadIdx.x >> 1;
    const int hf = threadIdx.x & 1;
    ushort4 m;
    m.x = s[hf * 4 + 0][co]; m.y = s[hf * 4 + 1][co];
    m.z = s[hf * 4 + 2][co]; m.w = s[hf * 4 + 3][co];
    *(ushort4*)&outG[b * DD + ((long)t * 128 + co) * DIM
                     + (long)ti * 128 + r0 + hf * 4] = m;
}

// ---------------------------------------------------------------------------
// Unified prep: z < BATCH -> x batch z: xb (cast) + xTb (transpose-cast);
// z == BATCH -> weights: y>>5 selects {Wq,Wk,Wv cast; P transpose}.
// ---------------------------------------------------------------------------
__global__ __launch_bounds__(256)
void prep_all(const float* __restrict__ x,
              const float* __restrict__ Wq, const float* __restrict__ Wk,
              const float* __restrict__ Wv, const float* __restrict__ P,
              unsigned short* __restrict__ xb, unsigned short* __restrict__ xTb,
              unsigned short* __restrict__ Wqb, unsigned short* __restrict__ Wkb,
              unsigned short* __restrict__ Wvb, unsigned short* __restrict__ Ptb)
{
    __shared__ unsigned short t[32][33];
    const int z = blockIdx.z;
    const int row = threadIdx.x >> 3;
    const int cid = threadIdx.x & 7;

    if (z < BATCH) {
        const long base = (long)z * SEQ * DIM;
        const int r0 = blockIdx.y * 32;      // over S
        const int c0 = blockIdx.x * 32;      // over D
        float4 v = *(const float4*)&x[base + (long)(r0 + row) * DIM + c0 + cid * 4];
        ushort4 h;
        h.x = f2bf(v.x); h.y = f2bf(v.y); h.z = f2bf(v.z); h.w = f2bf(v.w);
        *(ushort4*)&xb[base + (long)(r0 + row) * DIM + c0 + cid * 4] = h;
        t[row][cid * 4 + 0] = h.x; t[row][cid * 4 + 1] = h.y;
        t[row][cid * 4 + 2] = h.z; t[row][cid * 4 + 3] = h.w;
        __syncthreads();
        ushort4 o;
        o.x = t[cid * 4 + 0][row];
        o.y = t[cid * 4 + 1][row];
        o.z = t[cid * 4 + 2][row];
        o.w = t[cid * 4 + 3][row];
        *(ushort4*)&xTb[base + (long)(c0 + row) * SEQ + r0 + cid * 4] = o;
        return;
    }

    const int wsel = blockIdx.y >> 5;        // 0=Wq 1=Wk 2=Wv 3=P
    const int r0 = (blockIdx.y & 31) * 32;
    const int c0 = blockIdx.x * 32;
    const float* src = (wsel == 0) ? Wq : (wsel == 1) ? Wk : (wsel == 2) ? Wv : P;
    float4 v = *(const float4*)&src[(long)(r0 + row) * DIM + c0 + cid * 4];
    ushort4 h;
    h.x = f2bf(v.x); h.y = f2bf(v.y); h.z = f2bf(v.z); h.w = f2bf(v.w);

    if (wsel < 3) {
        unsigned short* dst = (wsel == 0) ? Wqb : (wsel == 1) ? Wkb : Wvb;
        *(ushort4*)&dst[(long)(r0 + row) * DIM + c0 + cid * 4] = h;
        return;
    }
    t[row][cid * 4 + 0] = h.x; t[row][cid * 4 + 1] = h.y;
    t[row][cid * 4 + 2] = h.z; t[row][cid * 4 + 3] = h.w;
    __syncthreads();
    ushort4 o;
    o.x = t[cid * 4 + 0][row];
    o.y = t[cid * 4 + 1][row];
    o.z = t[cid * 4 + 2][row];
    o.w = t[cid * 4 + 3][row];
    *(ushort4*)&Ptb[(long)(c0 + row) * DIM + r0 + cid * 4] = o;
}

// ---------------------------------------------------------------------------
extern "C" void kernel_launch(void* const* d_in, const int* in_sizes, int n_in,
                              void* d_out, int out_size, void* d_ws, size_t ws_size,
                              hipStream_t stream)
{
    const float* x  = (const float*)d_in[0];
    const float* Wq = (const float*)d_in[1];
    const float* Wk = (const float*)d_in[2];
    const float* Wv = (const float*)d_in[3];
    const float* P  = (const float*)d_in[4];
    float* out = (float*)d_out;

    const long DD = (long)DIM * DIM;
    const long SD = (long)SEQ * DIM;

    // workspace layout (MiB offsets) — proven map; regA bf16 (36 MiB):
    //   [0,32) xb | [32,64) xTb -> Hb[32,40) Ntb[40,48)
    //   [64,72) Gb | [72,84) weights | [84,120) regA gram bf16 partials
    uint8_t* ws = (uint8_t*)d_ws;
    unsigned short* xb   = (unsigned short*)(ws);
    unsigned short* xTb  = (unsigned short*)(ws + (32ul << 20));
    unsigned short* Hb   = (unsigned short*)(ws + (32ul << 20));
    unsigned short* Ntb  = (unsigned short*)(ws + (40ul << 20));
    unsigned short* Gb   = (unsigned short*)(ws + (64ul << 20));
    unsigned short* Wqb  = (unsigned short*)(ws + (72ul << 20));
    unsigned short* Ptb  = (unsigned short*)(ws + (74ul << 20));
    unsigned short* Wkb  = (unsigned short*)(ws + (76ul << 20));
    unsigned short* Wvb  = (unsigned short*)(ws + (78ul << 20));
    unsigned short* Ub   = (unsigned short*)(ws + (80ul << 20));
    unsigned short* W2Tb = (unsigned short*)(ws + (82ul << 20));
    unsigned short* regA = (unsigned short*)(ws + (84ul << 20));

    const int split = 8;   // bf16 partials: 36 MiB

    // 1) x -> xb, xTb ; Wq/Wk/Wv -> bf16 ; P -> Pt   (single launch)
    prep_all<<<dim3(DIM / 32, SEQ / 32, BATCH + 1), 256, 0, stream>>>(
        x, Wq, Wk, Wv, P, xb, xTb, Wqb, Wkb, Wvb, Ptb);

    // 2) G_b = xT_b @ xT_b^T — lower tiles, split-K bf16 partials;
    //    reduce also writes the symmetric mirror
    gemm_db<3, 128, true, false><<<dim3(36 * split * BATCH, 1, 1), 256, 0, stream>>>(
        xTb, xTb, regA, SEQ / split, split, SEQ, SEQ, DIM, SD, SD, 0);
    reduce_cast_tri<<<dim3(BATCH * 36 * 128 * 32 / 256), 256, 0, stream>>>(
        regA, Gb, split);

    // 3) {U, W2T} in one z=2 launch, split=1: U = Wq@Wk^T ; W2T = Pt@Wv^T
    gemm_db<1, 64, false, false><<<dim3(16, 8, 2), 256, 0, stream>>>(
        Wqb, Wkb, Ub, DIM, 1, DIM, DIM, DIM, DD, DD, DD);

    // 4) H_b = U @ G_b^T  (G symmetric)
    gemm_db<1, 64, false, false><<<dim3(16, 8, BATCH), 256, 0, stream>>>(
        Ub, Gb, Hb, DIM, 1, DIM, DIM, DIM, 0, DD, DD);

    // 5) Nt_b = W2T @ H_b^T + I   (residual folded in)
    gemm_db<1, 64, false, true><<<dim3(16, 8, BATCH), 256, 0, stream>>>(
        W2Tb, Hb, Ntb, DIM, 1, DIM, DIM, DIM, 0, DD, DD);

    // 6) out_b = xb_b @ Nt_b^T  (fp32 out, A-LDS prefetch-3 + B-from-L2-regs)
    gemm_fin<<<dim3(DIM / 256, SEQ / 128, BATCH), 256, 0, stream>>>(
        xb, Ntb, out, DIM, DIM, DIM, DIM, SD, DD, SD);
}

// Round 19
// 163.310 us; speedup vs baseline: 1.2173x; 1.2173x over previous
//
#include <hip/hip_runtime.h>
#include <hip/hip_bf16.h>
#include <stdint.h>

// out = x + x * [ (Wq Wk^T) * (x^T x) * (Wv P) ]  ==  x @ (I + N),  N = U G W2
// Final GEMM: 256x256 8-wave 2-cluster counted-vmcnt pipeline (best measured,
// rounds 11-13; round-18's B-from-global regressed and is reverted).
// Gram: 128^2 pipeline, bf16 split-K partials + fused symmetric mirror.
// Weights GEMM split=1. Prep fused into one launch.

#define BATCH 4
#define SEQ   4096
#define DIM   1024

#define TRI_SLICE 589824l       // 36 tiles * 128*128 elements per gram slice

typedef __bf16 bf16x8 __attribute__((ext_vector_type(8)));
typedef float f32x4 __attribute__((ext_vector_type(4)));

static __device__ __forceinline__ unsigned short f2bf(float f) {
    unsigned int u = __builtin_bit_cast(unsigned int, f);
    u += 0x7fff + ((u >> 16) & 1);              // RNE
    return (unsigned short)(u >> 16);
}
static __device__ __forceinline__ float bf2f(unsigned short h) {
    unsigned int u = (unsigned int)h << 16;
    return __builtin_bit_cast(float, u);
}

// ---------------------------------------------------------------------------
// 256x256-tile deep-pipelined bf16 MFMA GEMM: C = A @ Bt^T (fp32 out).
//  512 threads = 8 waves (2M x 4N), per-wave 128x64 output.
//  LDS [2][256][64] x2 = 128 KiB (1 block/CU). vmcnt(8) counted protocol.
//  Grid: (N/256, M/256, BATCH); flattened nwg % 8 == 0. K/64 >= 2.
// ---------------------------------------------------------------------------
__global__ __launch_bounds__(512)
void gemm_db256(const unsigned short* __restrict__ Ag,
                const unsigned short* __restrict__ Btg,
                float* __restrict__ Cg,
                int K, int lda, int ldbt, int ldc,
                long sA, long sBt, long sC)
{
    __shared__ unsigned short As[2][256][64];
    __shared__ unsigned short Bs[2][256][64];

    const int gx = gridDim.x, gy = gridDim.y;
    const int nwg = gx * gy * gridDim.z;
    int id = blockIdx.x + gx * (blockIdx.y + gy * blockIdx.z);
    id = (id & 7) * (nwg >> 3) + (id >> 3);

    const int bx = id % gx;
    const int rest = id / gx;
    const int by = rest % gy;
    const int b = rest / gy;
    const long i0 = (long)by * 256;
    const long j0 = (long)bx * 256;

    const unsigned short* A  = Ag  + (long)b * sA;
    const unsigned short* Bt = Btg + (long)b * sBt;

    const int tid  = threadIdx.x;
    const int lane = tid & 63;
    const int w    = tid >> 6;          // wave 0..7
    const int wr   = w >> 2;            // 0..1  (M half)
    const int wc   = w & 3;             // 0..3  (N quarter)
    const int lrow = lane >> 3;         // 0..7
    const int lcol = lane & 7;          // 0..7 (16B granule)
    const int fr   = lane & 15;
    const int kg   = lane >> 4;         // 0..3
    const int scol = (lcol ^ lrow) * 8; // pre-swizzled global source chunk

    f32x4 acc[8][4] = {};

    const int nt = K / 64;

    auto stage = [&](int t, int buf) {
        const long kk = (long)t * 64;
#pragma unroll
        for (int inst = 0; inst < 4; ++inst) {
            const int row = w * 32 + inst * 8;
            const unsigned short* srcA = A + (i0 + row + lrow) * lda + kk + scol;
            __builtin_amdgcn_global_load_lds(
                (const __attribute__((address_space(1))) void*)srcA,
                (__attribute__((address_space(3))) void*)&As[buf][row][0], 16, 0, 0);
            const unsigned short* srcB = Bt + (j0 + row + lrow) * ldbt + kk + scol;
            __builtin_amdgcn_global_load_lds(
                (const __attribute__((address_space(1))) void*)srcB,
                (__attribute__((address_space(3))) void*)&Bs[buf][row][0], 16, 0, 0);
        }
    };

    stage(0, 0);
    stage(1, 1);

    for (int t = 0; t < nt; ++t) {
        const int buf = t & 1;
        if (t < nt - 1) asm volatile("s_waitcnt vmcnt(8)" ::: "memory");
        else            asm volatile("s_waitcnt vmcnt(0)" ::: "memory");
        __builtin_amdgcn_s_barrier();
        asm volatile("" ::: "memory");

        // ---- cluster 0: reads (12 x b128) + MFMA (32)
        const int ch0 = (kg ^ (fr & 7)) * 8;
        bf16x8 af0[8], bf0[4];
#pragma unroll
        for (int m = 0; m < 8; ++m)
            af0[m] = *(const bf16x8*)&As[buf][wr * 128 + m * 16 + fr][ch0];
#pragma unroll
        for (int n = 0; n < 4; ++n)
            bf0[n] = *(const bf16x8*)&Bs[buf][wc * 64 + n * 16 + fr][ch0];
        __builtin_amdgcn_s_setprio(1);
#pragma unroll
        for (int m = 0; m < 8; ++m)
#pragma unroll
            for (int n = 0; n < 4; ++n)
                acc[m][n] = __builtin_amdgcn_mfma_f32_16x16x32_bf16(
                    af0[m], bf0[n], acc[m][n], 0, 0, 0);
        __builtin_amdgcn_s_setprio(0);

        // ---- cluster 1 reads
        const int ch1 = ((4 + kg) ^ (fr & 7)) * 8;
        bf16x8 af1[8], bf1[4];
#pragma unroll
        for (int m = 0; m < 8; ++m)
            af1[m] = *(const bf16x8*)&As[buf][wr * 128 + m * 16 + fr][ch1];
#pragma unroll
        for (int n = 0; n < 4; ++n)
            bf1[n] = *(const bf16x8*)&Bs[buf][wc * 64 + n * 16 + fr][ch1];

        asm volatile("s_waitcnt lgkmcnt(0)" ::: "memory");
        __builtin_amdgcn_sched_barrier(0);
        __builtin_amdgcn_s_barrier();          // all waves done reading buf
        asm volatile("" ::: "memory");

        if (t + 2 < nt) stage(t + 2, buf);     // loads fly under MFMA cluster 1
        __builtin_amdgcn_sched_barrier(0);

        __builtin_amdgcn_s_setprio(1);
#pragma unroll
        for (int m = 0; m < 8; ++m)
#pragma unroll
            for (int n = 0; n < 4; ++n)
                acc[m][n] = __builtin_amdgcn_mfma_f32_16x16x32_bf16(
                    af1[m], bf1[n], acc[m][n], 0, 0, 0);
        __builtin_amdgcn_s_setprio(0);
    }

    // ---- epilogue: C/D layout col = lane&15, row = (lane>>4)*4 + q
    float* C32 = Cg + (long)b * sC;
#pragma unroll
    for (int m = 0; m < 8; ++m) {
        const long rbase = i0 + wr * 128 + m * 16 + kg * 4;
#pragma unroll
        for (int n = 0; n < 4; ++n) {
            const long col = j0 + wc * 64 + n * 16 + fr;
#pragma unroll
            for (int q = 0; q < 4; ++q)
                C32[(rbase + q) * ldc + col] = acc[m][n][q];
        }
    }
}

// ---------------------------------------------------------------------------
// 128 x BN deep-pipelined bf16 MFMA GEMM (proven rounds 9-17) — gram + chain.
//  OUTMODE: 0 fp32 out; 1 bf16 out (+ADD_I); 3 TRI compact BF16 partial.
// ---------------------------------------------------------------------------
template<int OUTMODE, int BN, bool TRI, bool ADD_I>
__global__ __launch_bounds__(256)
void gemm_db(const unsigned short* __restrict__ Ag,
             const unsigned short* __restrict__ Btg,
             void* __restrict__ Cg,
             int K, int zdiv, int lda, int ldbt, int ldc,
             long sA, long sBt, long sC)
{
    constexpr int NF = BN / 32;             // B fragments per wave (2 or 4)
    __shared__ unsigned short As[2][128][64];
    __shared__ unsigned short Bs[2][BN][64];

    const int gx = gridDim.x, gy = gridDim.y;
    const int nwg = gx * gy * gridDim.z;
    int id = blockIdx.x + gx * (blockIdx.y + gy * blockIdx.z);
    id = (id & 7) * (nwg >> 3) + (id >> 3);

    int z, tlin = 0;
    long i0, j0;
    if (TRI) {
        z = id / 36;
        tlin = id % 36;
        int t = tlin, ti = 0;
        while (t > ti) { t -= ti + 1; ++ti; }
        i0 = (long)ti * 128;
        j0 = (long)t * 128;
    } else {
        const int bx = id % gx;
        const int rest = id / gx;
        const int by = rest % gy;
        z = rest / gy;
        i0 = (long)by * 128;
        j0 = (long)bx * BN;
    }
    const int b = z / zdiv;
    const long koff = (long)(z % zdiv) * K;

    const unsigned short* A  = Ag  + (long)b * sA  + koff;
    const unsigned short* Bt = Btg + (long)b * sBt + koff;

    const int tid  = threadIdx.x;
    const int lane = tid & 63;
    const int w    = tid >> 6;          // wave 0..3
    const int wr   = w >> 1, wc = w & 1;
    const int lrow = lane >> 3;         // 0..7
    const int lcol = lane & 7;          // 0..7 (16B granule)
    const int fr   = lane & 15;
    const int kg   = lane >> 4;         // 0..3
    const int scol = (lcol ^ lrow) * 8; // pre-swizzled global source chunk

    f32x4 acc[4][NF] = {};

    const int nt = K / 64;              // >= 2 always

    auto stage = [&](int t, int buf) {
        const long kk = (long)t * 64;
#pragma unroll
        for (int inst = 0; inst < 4; ++inst) {
            const int row = w * 32 + inst * 8;
            const unsigned short* srcA = A + (i0 + row + lrow) * lda + kk + scol;
            __builtin_amdgcn_global_load_lds(
                (const __attribute__((address_space(1))) void*)srcA,
                (__attribute__((address_space(3))) void*)&As[buf][row][0], 16, 0, 0);
        }
#pragma unroll
        for (int inst = 0; inst < NF; ++inst) {
            const int row = w * (8 * NF) + inst * 8;
            const unsigned short* srcB = Bt + (j0 + row + lrow) * ldbt + kk + scol;
            __builtin_amdgcn_global_load_lds(
                (const __attribute__((address_space(1))) void*)srcB,
                (__attribute__((address_space(3))) void*)&Bs[buf][row][0], 16, 0, 0);
        }
    };

    stage(0, 0);
    stage(1, 1);

    for (int t = 0; t < nt; ++t) {
        const int buf = t & 1;
        if (t < nt - 1) {
            if constexpr (BN == 128)
                asm volatile("s_waitcnt vmcnt(8)" ::: "memory");
            else
                asm volatile("s_waitcnt vmcnt(6)" ::: "memory");
        } else {
            asm volatile("s_waitcnt vmcnt(0)" ::: "memory");
        }
        __builtin_amdgcn_s_barrier();
        asm volatile("" ::: "memory");

        bf16x8 af0[4], bf0[NF], af1[4], bf1[NF];
        const int ch0 = (kg ^ (fr & 7)) * 8;
        const int ch1 = ((4 + kg) ^ (fr & 7)) * 8;
#pragma unroll
        for (int m = 0; m < 4; ++m)
            af0[m] = *(const bf16x8*)&As[buf][wr * 64 + m * 16 + fr][ch0];
#pragma unroll
        for (int n = 0; n < NF; ++n)
            bf0[n] = *(const bf16x8*)&Bs[buf][wc * (BN / 2) + n * 16 + fr][ch0];
#pragma unroll
        for (int m = 0; m < 4; ++m)
            af1[m] = *(const bf16x8*)&As[buf][wr * 64 + m * 16 + fr][ch1];
#pragma unroll
        for (int n = 0; n < NF; ++n)
            bf1[n] = *(const bf16x8*)&Bs[buf][wc * (BN / 2) + n * 16 + fr][ch1];

        __builtin_amdgcn_s_setprio(1);
#pragma unroll
        for (int m = 0; m < 4; ++m)
#pragma unroll
            for (int n = 0; n < NF; ++n)
                acc[m][n] = __builtin_amdgcn_mfma_f32_16x16x32_bf16(
                    af0[m], bf0[n], acc[m][n], 0, 0, 0);
        __builtin_amdgcn_s_setprio(0);

        asm volatile("s_waitcnt lgkmcnt(0)" ::: "memory");
        __builtin_amdgcn_sched_barrier(0);
        __builtin_amdgcn_s_barrier();
        asm volatile("" ::: "memory");

        if (t + 2 < nt) stage(t + 2, buf);
        __builtin_amdgcn_sched_barrier(0);

        __builtin_amdgcn_s_setprio(1);
#pragma unroll
        for (int m = 0; m < 4; ++m)
#pragma unroll
            for (int n = 0; n < NF; ++n)
                acc[m][n] = __builtin_amdgcn_mfma_f32_16x16x32_bf16(
                    af1[m], bf1[n], acc[m][n], 0, 0, 0);
        __builtin_amdgcn_s_setprio(0);
    }

    if (OUTMODE == 3) {
        unsigned short* Cp = (unsigned short*)Cg + (long)z * TRI_SLICE
                           + (long)tlin * 16384;
#pragma unroll
        for (int m = 0; m < 4; ++m) {
            const int lrb = wr * 64 + m * 16 + kg * 4;
#pragma unroll
            for (int n = 0; n < NF; ++n) {
                const int lc = wc * (BN / 2) + n * 16 + fr;
#pragma unroll
                for (int q = 0; q < 4; ++q)
                    Cp[(lrb + q) * 128 + lc] = f2bf(acc[m][n][q]);
            }
        }
        return;
    }

    unsigned short* C16 = (OUTMODE == 1) ? ((unsigned short*)Cg + (long)b * sC) : nullptr;
    float*          C32 = (OUTMODE == 0) ? ((float*)Cg + (long)b * sC) : nullptr;
#pragma unroll
    for (int m = 0; m < 4; ++m) {
        const long rbase = i0 + wr * 64 + m * 16 + kg * 4;
#pragma unroll
        for (int n = 0; n < NF; ++n) {
            const long col = j0 + wc * (BN / 2) + n * 16 + fr;
#pragma unroll
            for (int q = 0; q < 4; ++q) {
                const long r = rbase + q;
                float v = acc[m][n][q];
                if (ADD_I && r == col) v += 1.0f;
                if (OUTMODE == 1) C16[r * ldc + col] = f2bf(v);
                else              C32[r * ldc + col] = v;
            }
        }
    }
}

// ---------------------------------------------------------------------------
// Reduce gram split-K BF16 compact partials -> bf16 G (lower tiles), AND
// write the strict-upper mirror (transposed strip via LDS).
// ---------------------------------------------------------------------------
__global__ __launch_bounds__(256)
void reduce_cast_tri(const unsigned short* __restrict__ part,
                     unsigned short* __restrict__ outG, int split)
{
    __shared__ unsigned short s[8][132];
    const long DD = (long)DIM * DIM;
    int id = blockIdx.x * 256 + threadIdx.x;
    const int b  = id / 147456;          // 36*128*32
    int rem      = id % 147456;
    const int tlin = rem / 4096;
    const int rr = rem % 4096;
    const int r  = rr >> 5;
    const int c4 = rr & 31;
    int t = tlin, ti = 0;
    while (t > ti) { t -= ti + 1; ++ti; }
    const long off = (long)tlin * 16384 + r * 128 + c4 * 4;

    float4 sum = make_float4(0.f, 0.f, 0.f, 0.f);
    for (int sp = 0; sp < split; ++sp) {
        ushort4 v = *(const ushort4*)&part[(long)(b * split + sp) * TRI_SLICE + off];
        sum.x += bf2f(v.x); sum.y += bf2f(v.y); sum.z += bf2f(v.z); sum.w += bf2f(v.w);
    }
    ushort4 o;
    o.x = f2bf(sum.x); o.y = f2bf(sum.y); o.z = f2bf(sum.z); o.w = f2bf(sum.w);
    *(ushort4*)&outG[b * DD + ((long)ti * 128 + r) * DIM + (long)t * 128 + c4 * 4] = o;

    if (t == ti) return;                 // diagonal tile: already complete

    const int rl = r & 7;
    s[rl][c4 * 4 + 0] = o.x; s[rl][c4 * 4 + 1] = o.y;
    s[rl][c4 * 4 + 2] = o.z; s[rl][c4 * 4 + 3] = o.w;
    __syncthreads();

    const int r0 = r & ~7;
    const int co = threadIdx.x >> 1;
    const int hf = threadIdx.x & 1;
    ushort4 m;
    m.x = s[hf * 4 + 0][co]; m.y = s[hf * 4 + 1][co];
    m.z = s[hf * 4 + 2][co]; m.w = s[hf * 4 + 3][co];
    *(ushort4*)&outG[b * DD + ((long)t * 128 + co) * DIM
                     + (long)ti * 128 + r0 + hf * 4] = m;
}

// ---------------------------------------------------------------------------
// Unified prep: z < BATCH -> x batch z: xb (cast) + xTb (transpose-cast);
// z == BATCH -> weights: y>>5 selects {Wq,Wk,Wv cast; P transpose}.
// ---------------------------------------------------------------------------
__global__ __launch_bounds__(256)
void prep_all(const float* __restrict__ x,
              const float* __restrict__ Wq, const float* __restrict__ Wk,
              const float* __restrict__ Wv, const float* __restrict__ P,
              unsigned short* __restrict__ xb, unsigned short* __restrict__ xTb,
              unsigned short* __restrict__ Wqb, unsigned short* __restrict__ Wkb,
              unsigned short* __restrict__ Wvb, unsigned short* __restrict__ Ptb)
{
    __shared__ unsigned short t[32][33];
    const int z = blockIdx.z;
    const int row = threadIdx.x >> 3;
    const int cid = threadIdx.x & 7;

    if (z < BATCH) {
        const long base = (long)z * SEQ * DIM;
        const int r0 = blockIdx.y * 32;      // over S
        const int c0 = blockIdx.x * 32;      // over D
        float4 v = *(const float4*)&x[base + (long)(r0 + row) * DIM + c0 + cid * 4];
        ushort4 h;
        h.x = f2bf(v.x); h.y = f2bf(v.y); h.z = f2bf(v.z); h.w = f2bf(v.w);
        *(ushort4*)&xb[base + (long)(r0 + row) * DIM + c0 + cid * 4] = h;
        t[row][cid * 4 + 0] = h.x; t[row][cid * 4 + 1] = h.y;
        t[row][cid * 4 + 2] = h.z; t[row][cid * 4 + 3] = h.w;
        __syncthreads();
        ushort4 o;
        o.x = t[cid * 4 + 0][row];
        o.y = t[cid * 4 + 1][row];
        o.z = t[cid * 4 + 2][row];
        o.w = t[cid * 4 + 3][row];
        *(ushort4*)&xTb[base + (long)(c0 + row) * SEQ + r0 + cid * 4] = o;
        return;
    }

    const int wsel = blockIdx.y >> 5;        // 0=Wq 1=Wk 2=Wv 3=P
    const int r0 = (blockIdx.y & 31) * 32;
    const int c0 = blockIdx.x * 32;
    const float* src = (wsel == 0) ? Wq : (wsel == 1) ? Wk : (wsel == 2) ? Wv : P;
    float4 v = *(const float4*)&src[(long)(r0 + row) * DIM + c0 + cid * 4];
    ushort4 h;
    h.x = f2bf(v.x); h.y = f2bf(v.y); h.z = f2bf(v.z); h.w = f2bf(v.w);

    if (wsel < 3) {
        unsigned short* dst = (wsel == 0) ? Wqb : (wsel == 1) ? Wkb : Wvb;
        *(ushort4*)&dst[(long)(r0 + row) * DIM + c0 + cid * 4] = h;
        return;
    }
    t[row][cid * 4 + 0] = h.x; t[row][cid * 4 + 1] = h.y;
    t[row][cid * 4 + 2] = h.z; t[row][cid * 4 + 3] = h.w;
    __syncthreads();
    ushort4 o;
    o.x = t[cid * 4 + 0][row];
    o.y = t[cid * 4 + 1][row];
    o.z = t[cid * 4 + 2][row];
    o.w = t[cid * 4 + 3][row];
    *(ushort4*)&Ptb[(long)(c0 + row) * DIM + r0 + cid * 4] = o;
}

// ---------------------------------------------------------------------------
extern "C" void kernel_launch(void* const* d_in, const int* in_sizes, int n_in,
                              void* d_out, int out_size, void* d_ws, size_t ws_size,
                              hipStream_t stream)
{
    const float* x  = (const float*)d_in[0];
    const float* Wq = (const float*)d_in[1];
    const float* Wk = (const float*)d_in[2];
    const float* Wv = (const float*)d_in[3];
    const float* P  = (const float*)d_in[4];
    float* out = (float*)d_out;

    const long DD = (long)DIM * DIM;
    const long SD = (long)SEQ * DIM;

    // workspace layout (MiB offsets) — proven map; regA bf16 (36 MiB):
    //   [0,32) xb | [32,64) xTb -> Hb[32,40) Ntb[40,48)
    //   [64,72) Gb | [72,84) weights | [84,120) regA gram bf16 partials
    uint8_t* ws = (uint8_t*)d_ws;
    unsigned short* xb   = (unsigned short*)(ws);
    unsigned short* xTb  = (unsigned short*)(ws + (32ul << 20));
    unsigned short* Hb   = (unsigned short*)(ws + (32ul << 20));
    unsigned short* Ntb  = (unsigned short*)(ws + (40ul << 20));
    unsigned short* Gb   = (unsigned short*)(ws + (64ul << 20));
    unsigned short* Wqb  = (unsigned short*)(ws + (72ul << 20));
    unsigned short* Ptb  = (unsigned short*)(ws + (74ul << 20));
    unsigned short* Wkb  = (unsigned short*)(ws + (76ul << 20));
    unsigned short* Wvb  = (unsigned short*)(ws + (78ul << 20));
    unsigned short* Ub   = (unsigned short*)(ws + (80ul << 20));
    unsigned short* W2Tb = (unsigned short*)(ws + (82ul << 20));
    unsigned short* regA = (unsigned short*)(ws + (84ul << 20));

    const int split = 8;   // bf16 partials: 36 MiB

    // 1) x -> xb, xTb ; Wq/Wk/Wv -> bf16 ; P -> Pt   (single launch)
    prep_all<<<dim3(DIM / 32, SEQ / 32, BATCH + 1), 256, 0, stream>>>(
        x, Wq, Wk, Wv, P, xb, xTb, Wqb, Wkb, Wvb, Ptb);

    // 2) G_b = xT_b @ xT_b^T — lower tiles, split-K bf16 partials;
    //    reduce also writes the symmetric mirror
    gemm_db<3, 128, true, false><<<dim3(36 * split * BATCH, 1, 1), 256, 0, stream>>>(
        xTb, xTb, regA, SEQ / split, split, SEQ, SEQ, DIM, SD, SD, 0);
    reduce_cast_tri<<<dim3(BATCH * 36 * 128 * 32 / 256), 256, 0, stream>>>(
        regA, Gb, split);

    // 3) {U, W2T} in one z=2 launch, split=1: U = Wq@Wk^T ; W2T = Pt@Wv^T
    gemm_db<1, 64, false, false><<<dim3(16, 8, 2), 256, 0, stream>>>(
        Wqb, Wkb, Ub, DIM, 1, DIM, DIM, DIM, DD, DD, DD);

    // 4) H_b = U @ G_b^T  (G symmetric)
    gemm_db<1, 64, false, false><<<dim3(16, 8, BATCH), 256, 0, stream>>>(
        Ub, Gb, Hb, DIM, 1, DIM, DIM, DIM, 0, DD, DD);

    // 5) Nt_b = W2T @ H_b^T + I   (residual folded in)
    gemm_db<1, 64, false, true><<<dim3(16, 8, BATCH), 256, 0, stream>>>(
        W2Tb, Hb, Ntb, DIM, 1, DIM, DIM, DIM, 0, DD, DD);

    // 6) out_b = xb_b @ Nt_b^T  (fp32 out, 256x256 2-cluster pipeline)
    gemm_db256<<<dim3(DIM / 256, SEQ / 256, BATCH), 512, 0, stream>>>(
        xb, Ntb, out, DIM, DIM, DIM, DIM, SD, DD, SD);
}

// Round 20
// 155.432 us; speedup vs baseline: 1.2790x; 1.0507x over previous
//
#include <hip/hip_runtime.h>
#include <hip/hip_bf16.h>
#include <stdint.h>

// out = x + x * [ (Wq Wk^T) * (x^T x) * (Wv P) ]  ==  x @ (I + N),  N = U G W2
// Final GEMM: 256x256 8-wave 2-cluster counted-vmcnt pipeline (best measured).
// Gram: 128^2 pipeline, bf16 split-K partials + fused symmetric mirror.
// Weights GEMM split=1. Prep: 4x-ILP strip version (32x128 per block).

#define BATCH 4
#define SEQ   4096
#define DIM   1024

#define TRI_SLICE 589824l       // 36 tiles * 128*128 elements per gram slice

typedef __bf16 bf16x8 __attribute__((ext_vector_type(8)));
typedef float f32x4 __attribute__((ext_vector_type(4)));

static __device__ __forceinline__ unsigned short f2bf(float f) {
    unsigned int u = __builtin_bit_cast(unsigned int, f);
    u += 0x7fff + ((u >> 16) & 1);              // RNE
    return (unsigned short)(u >> 16);
}
static __device__ __forceinline__ float bf2f(unsigned short h) {
    unsigned int u = (unsigned int)h << 16;
    return __builtin_bit_cast(float, u);
}

// ---------------------------------------------------------------------------
// 256x256-tile deep-pipelined bf16 MFMA GEMM: C = A @ Bt^T (fp32 out).
//  512 threads = 8 waves (2M x 4N), per-wave 128x64 output.
//  LDS [2][256][64] x2 = 128 KiB (1 block/CU). vmcnt(8) counted protocol.
//  Grid: (N/256, M/256, BATCH); flattened nwg % 8 == 0. K/64 >= 2.
// ---------------------------------------------------------------------------
__global__ __launch_bounds__(512)
void gemm_db256(const unsigned short* __restrict__ Ag,
                const unsigned short* __restrict__ Btg,
                float* __restrict__ Cg,
                int K, int lda, int ldbt, int ldc,
                long sA, long sBt, long sC)
{
    __shared__ unsigned short As[2][256][64];
    __shared__ unsigned short Bs[2][256][64];

    const int gx = gridDim.x, gy = gridDim.y;
    const int nwg = gx * gy * gridDim.z;
    int id = blockIdx.x + gx * (blockIdx.y + gy * blockIdx.z);
    id = (id & 7) * (nwg >> 3) + (id >> 3);

    const int bx = id % gx;
    const int rest = id / gx;
    const int by = rest % gy;
    const int b = rest / gy;
    const long i0 = (long)by * 256;
    const long j0 = (long)bx * 256;

    const unsigned short* A  = Ag  + (long)b * sA;
    const unsigned short* Bt = Btg + (long)b * sBt;

    const int tid  = threadIdx.x;
    const int lane = tid & 63;
    const int w    = tid >> 6;          // wave 0..7
    const int wr   = w >> 2;            // 0..1  (M half)
    const int wc   = w & 3;             // 0..3  (N quarter)
    const int lrow = lane >> 3;         // 0..7
    const int lcol = lane & 7;          // 0..7 (16B granule)
    const int fr   = lane & 15;
    const int kg   = lane >> 4;         // 0..3
    const int scol = (lcol ^ lrow) * 8; // pre-swizzled global source chunk

    f32x4 acc[8][4] = {};

    const int nt = K / 64;

    auto stage = [&](int t, int buf) {
        const long kk = (long)t * 64;
#pragma unroll
        for (int inst = 0; inst < 4; ++inst) {
            const int row = w * 32 + inst * 8;
            const unsigned short* srcA = A + (i0 + row + lrow) * lda + kk + scol;
            __builtin_amdgcn_global_load_lds(
                (const __attribute__((address_space(1))) void*)srcA,
                (__attribute__((address_space(3))) void*)&As[buf][row][0], 16, 0, 0);
            const unsigned short* srcB = Bt + (j0 + row + lrow) * ldbt + kk + scol;
            __builtin_amdgcn_global_load_lds(
                (const __attribute__((address_space(1))) void*)srcB,
                (__attribute__((address_space(3))) void*)&Bs[buf][row][0], 16, 0, 0);
        }
    };

    stage(0, 0);
    stage(1, 1);

    for (int t = 0; t < nt; ++t) {
        const int buf = t & 1;
        if (t < nt - 1) asm volatile("s_waitcnt vmcnt(8)" ::: "memory");
        else            asm volatile("s_waitcnt vmcnt(0)" ::: "memory");
        __builtin_amdgcn_s_barrier();
        asm volatile("" ::: "memory");

        // ---- cluster 0: reads (12 x b128) + MFMA (32)
        const int ch0 = (kg ^ (fr & 7)) * 8;
        bf16x8 af0[8], bf0[4];
#pragma unroll
        for (int m = 0; m < 8; ++m)
            af0[m] = *(const bf16x8*)&As[buf][wr * 128 + m * 16 + fr][ch0];
#pragma unroll
        for (int n = 0; n < 4; ++n)
            bf0[n] = *(const bf16x8*)&Bs[buf][wc * 64 + n * 16 + fr][ch0];
        __builtin_amdgcn_s_setprio(1);
#pragma unroll
        for (int m = 0; m < 8; ++m)
#pragma unroll
            for (int n = 0; n < 4; ++n)
                acc[m][n] = __builtin_amdgcn_mfma_f32_16x16x32_bf16(
                    af0[m], bf0[n], acc[m][n], 0, 0, 0);
        __builtin_amdgcn_s_setprio(0);

        // ---- cluster 1 reads
        const int ch1 = ((4 + kg) ^ (fr & 7)) * 8;
        bf16x8 af1[8], bf1[4];
#pragma unroll
        for (int m = 0; m < 8; ++m)
            af1[m] = *(const bf16x8*)&As[buf][wr * 128 + m * 16 + fr][ch1];
#pragma unroll
        for (int n = 0; n < 4; ++n)
            bf1[n] = *(const bf16x8*)&Bs[buf][wc * 64 + n * 16 + fr][ch1];

        asm volatile("s_waitcnt lgkmcnt(0)" ::: "memory");
        __builtin_amdgcn_sched_barrier(0);
        __builtin_amdgcn_s_barrier();          // all waves done reading buf
        asm volatile("" ::: "memory");

        if (t + 2 < nt) stage(t + 2, buf);     // loads fly under MFMA cluster 1
        __builtin_amdgcn_sched_barrier(0);

        __builtin_amdgcn_s_setprio(1);
#pragma unroll
        for (int m = 0; m < 8; ++m)
#pragma unroll
            for (int n = 0; n < 4; ++n)
                acc[m][n] = __builtin_amdgcn_mfma_f32_16x16x32_bf16(
                    af1[m], bf1[n], acc[m][n], 0, 0, 0);
        __builtin_amdgcn_s_setprio(0);
    }

    // ---- epilogue: C/D layout col = lane&15, row = (lane>>4)*4 + q
    float* C32 = Cg + (long)b * sC;
#pragma unroll
    for (int m = 0; m < 8; ++m) {
        const long rbase = i0 + wr * 128 + m * 16 + kg * 4;
#pragma unroll
        for (int n = 0; n < 4; ++n) {
            const long col = j0 + wc * 64 + n * 16 + fr;
#pragma unroll
            for (int q = 0; q < 4; ++q)
                C32[(rbase + q) * ldc + col] = acc[m][n][q];
        }
    }
}

// ---------------------------------------------------------------------------
// 128 x BN deep-pipelined bf16 MFMA GEMM (proven rounds 9-19) — gram + chain.
//  OUTMODE: 0 fp32 out; 1 bf16 out (+ADD_I); 3 TRI compact BF16 partial.
// ---------------------------------------------------------------------------
template<int OUTMODE, int BN, bool TRI, bool ADD_I>
__global__ __launch_bounds__(256)
void gemm_db(const unsigned short* __restrict__ Ag,
             const unsigned short* __restrict__ Btg,
             void* __restrict__ Cg,
             int K, int zdiv, int lda, int ldbt, int ldc,
             long sA, long sBt, long sC)
{
    constexpr int NF = BN / 32;             // B fragments per wave (2 or 4)
    __shared__ unsigned short As[2][128][64];
    __shared__ unsigned short Bs[2][BN][64];

    const int gx = gridDim.x, gy = gridDim.y;
    const int nwg = gx * gy * gridDim.z;
    int id = blockIdx.x + gx * (blockIdx.y + gy * blockIdx.z);
    id = (id & 7) * (nwg >> 3) + (id >> 3);

    int z, tlin = 0;
    long i0, j0;
    if (TRI) {
        z = id / 36;
        tlin = id % 36;
        int t = tlin, ti = 0;
        while (t > ti) { t -= ti + 1; ++ti; }
        i0 = (long)ti * 128;
        j0 = (long)t * 128;
    } else {
        const int bx = id % gx;
        const int rest = id / gx;
        const int by = rest % gy;
        z = rest / gy;
        i0 = (long)by * 128;
        j0 = (long)bx * BN;
    }
    const int b = z / zdiv;
    const long koff = (long)(z % zdiv) * K;

    const unsigned short* A  = Ag  + (long)b * sA  + koff;
    const unsigned short* Bt = Btg + (long)b * sBt + koff;

    const int tid  = threadIdx.x;
    const int lane = tid & 63;
    const int w    = tid >> 6;          // wave 0..3
    const int wr   = w >> 1, wc = w & 1;
    const int lrow = lane >> 3;         // 0..7
    const int lcol = lane & 7;          // 0..7 (16B granule)
    const int fr   = lane & 15;
    const int kg   = lane >> 4;         // 0..3
    const int scol = (lcol ^ lrow) * 8; // pre-swizzled global source chunk

    f32x4 acc[4][NF] = {};

    const int nt = K / 64;              // >= 2 always

    auto stage = [&](int t, int buf) {
        const long kk = (long)t * 64;
#pragma unroll
        for (int inst = 0; inst < 4; ++inst) {
            const int row = w * 32 + inst * 8;
            const unsigned short* srcA = A + (i0 + row + lrow) * lda + kk + scol;
            __builtin_amdgcn_global_load_lds(
                (const __attribute__((address_space(1))) void*)srcA,
                (__attribute__((address_space(3))) void*)&As[buf][row][0], 16, 0, 0);
        }
#pragma unroll
        for (int inst = 0; inst < NF; ++inst) {
            const int row = w * (8 * NF) + inst * 8;
            const unsigned short* srcB = Bt + (j0 + row + lrow) * ldbt + kk + scol;
            __builtin_amdgcn_global_load_lds(
                (const __attribute__((address_space(1))) void*)srcB,
                (__attribute__((address_space(3))) void*)&Bs[buf][row][0], 16, 0, 0);
        }
    };

    stage(0, 0);
    stage(1, 1);

    for (int t = 0; t < nt; ++t) {
        const int buf = t & 1;
        if (t < nt - 1) {
            if constexpr (BN == 128)
                asm volatile("s_waitcnt vmcnt(8)" ::: "memory");
            else
                asm volatile("s_waitcnt vmcnt(6)" ::: "memory");
        } else {
            asm volatile("s_waitcnt vmcnt(0)" ::: "memory");
        }
        __builtin_amdgcn_s_barrier();
        asm volatile("" ::: "memory");

        bf16x8 af0[4], bf0[NF], af1[4], bf1[NF];
        const int ch0 = (kg ^ (fr & 7)) * 8;
        const int ch1 = ((4 + kg) ^ (fr & 7)) * 8;
#pragma unroll
        for (int m = 0; m < 4; ++m)
            af0[m] = *(const bf16x8*)&As[buf][wr * 64 + m * 16 + fr][ch0];
#pragma unroll
        for (int n = 0; n < NF; ++n)
            bf0[n] = *(const bf16x8*)&Bs[buf][wc * (BN / 2) + n * 16 + fr][ch0];
#pragma unroll
        for (int m = 0; m < 4; ++m)
            af1[m] = *(const bf16x8*)&As[buf][wr * 64 + m * 16 + fr][ch1];
#pragma unroll
        for (int n = 0; n < NF; ++n)
            bf1[n] = *(const bf16x8*)&Bs[buf][wc * (BN / 2) + n * 16 + fr][ch1];

        __builtin_amdgcn_s_setprio(1);
#pragma unroll
        for (int m = 0; m < 4; ++m)
#pragma unroll
            for (int n = 0; n < NF; ++n)
                acc[m][n] = __builtin_amdgcn_mfma_f32_16x16x32_bf16(
                    af0[m], bf0[n], acc[m][n], 0, 0, 0);
        __builtin_amdgcn_s_setprio(0);

        asm volatile("s_waitcnt lgkmcnt(0)" ::: "memory");
        __builtin_amdgcn_sched_barrier(0);
        __builtin_amdgcn_s_barrier();
        asm volatile("" ::: "memory");

        if (t + 2 < nt) stage(t + 2, buf);
        __builtin_amdgcn_sched_barrier(0);

        __builtin_amdgcn_s_setprio(1);
#pragma unroll
        for (int m = 0; m < 4; ++m)
#pragma unroll
            for (int n = 0; n < NF; ++n)
                acc[m][n] = __builtin_amdgcn_mfma_f32_16x16x32_bf16(
                    af1[m], bf1[n], acc[m][n], 0, 0, 0);
        __builtin_amdgcn_s_setprio(0);
    }

    if (OUTMODE == 3) {
        unsigned short* Cp = (unsigned short*)Cg + (long)z * TRI_SLICE
                           + (long)tlin * 16384;
#pragma unroll
        for (int m = 0; m < 4; ++m) {
            const int lrb = wr * 64 + m * 16 + kg * 4;
#pragma unroll
            for (int n = 0; n < NF; ++n) {
                const int lc = wc * (BN / 2) + n * 16 + fr;
#pragma unroll
                for (int q = 0; q < 4; ++q)
                    Cp[(lrb + q) * 128 + lc] = f2bf(acc[m][n][q]);
            }
        }
        return;
    }

    unsigned short* C16 = (OUTMODE == 1) ? ((unsigned short*)Cg + (long)b * sC) : nullptr;
    float*          C32 = (OUTMODE == 0) ? ((float*)Cg + (long)b * sC) : nullptr;
#pragma unroll
    for (int m = 0; m < 4; ++m) {
        const long rbase = i0 + wr * 64 + m * 16 + kg * 4;
#pragma unroll
        for (int n = 0; n < NF; ++n) {
            const long col = j0 + wc * (BN / 2) + n * 16 + fr;
#pragma unroll
            for (int q = 0; q < 4; ++q) {
                const long r = rbase + q;
                float v = acc[m][n][q];
                if (ADD_I && r == col) v += 1.0f;
                if (OUTMODE == 1) C16[r * ldc + col] = f2bf(v);
                else              C32[r * ldc + col] = v;
            }
        }
    }
}

// ---------------------------------------------------------------------------
// Reduce gram split-K BF16 compact partials -> bf16 G (lower tiles), AND
// write the strict-upper mirror (transposed strip via LDS).
// ---------------------------------------------------------------------------
__global__ __launch_bounds__(256)
void reduce_cast_tri(const unsigned short* __restrict__ part,
                     unsigned short* __restrict__ outG, int split)
{
    __shared__ unsigned short s[8][132];
    const long DD = (long)DIM * DIM;
    int id = blockIdx.x * 256 + threadIdx.x;
    const int b  = id / 147456;          // 36*128*32
    int rem      = id % 147456;
    const int tlin = rem / 4096;
    const int rr = rem % 4096;
    const int r  = rr >> 5;
    const int c4 = rr & 31;
    int t = tlin, ti = 0;
    while (t > ti) { t -= ti + 1; ++ti; }
    const long off = (long)tlin * 16384 + r * 128 + c4 * 4;

    float4 sum = make_float4(0.f, 0.f, 0.f, 0.f);
    for (int sp = 0; sp < split; ++sp) {
        ushort4 v = *(const ushort4*)&part[(long)(b * split + sp) * TRI_SLICE + off];
        sum.x += bf2f(v.x); sum.y += bf2f(v.y); sum.z += bf2f(v.z); sum.w += bf2f(v.w);
    }
    ushort4 o;
    o.x = f2bf(sum.x); o.y = f2bf(sum.y); o.z = f2bf(sum.z); o.w = f2bf(sum.w);
    *(ushort4*)&outG[b * DD + ((long)ti * 128 + r) * DIM + (long)t * 128 + c4 * 4] = o;

    if (t == ti) return;                 // diagonal tile: already complete

    const int rl = r & 7;
    s[rl][c4 * 4 + 0] = o.x; s[rl][c4 * 4 + 1] = o.y;
    s[rl][c4 * 4 + 2] = o.z; s[rl][c4 * 4 + 3] = o.w;
    __syncthreads();

    const int r0 = r & ~7;
    const int co = threadIdx.x >> 1;
    const int hf = threadIdx.x & 1;
    ushort4 m;
    m.x = s[hf * 4 + 0][co]; m.y = s[hf * 4 + 1][co];
    m.z = s[hf * 4 + 2][co]; m.w = s[hf * 4 + 3][co];
    *(ushort4*)&outG[b * DD + ((long)t * 128 + co) * DIM
                     + (long)ti * 128 + r0 + hf * 4] = m;
}

// ---------------------------------------------------------------------------
// Unified prep, 4x ILP: each block covers a 32-row x 128-col strip
// (4 consecutive 32x32 tiles). z < BATCH: x batch z -> xb + xTb.
// z == BATCH: weights; y>>5 selects {Wq,Wk,Wv cast; P transpose}.
// Grid (DIM/128, SEQ/32, BATCH+1).
// ---------------------------------------------------------------------------
__global__ __launch_bounds__(256)
void prep_all(const float* __restrict__ x,
              const float* __restrict__ Wq, const float* __restrict__ Wk,
              const float* __restrict__ Wv, const float* __restrict__ P,
              unsigned short* __restrict__ xb, unsigned short* __restrict__ xTb,
              unsigned short* __restrict__ Wqb, unsigned short* __restrict__ Wkb,
              unsigned short* __restrict__ Wvb, unsigned short* __restrict__ Ptb)
{
    __shared__ unsigned short t[4][32][33];
    const int z = blockIdx.z;
    const int row = threadIdx.x >> 3;
    const int cid = threadIdx.x & 7;

    if (z < BATCH) {
        const long base = (long)z * SEQ * DIM;
        const int r0 = blockIdx.y * 32;      // over S
        const int c0 = blockIdx.x * 128;     // over D
        ushort4 h[4];
#pragma unroll
        for (int i = 0; i < 4; ++i) {
            float4 v = *(const float4*)&x[base + (long)(r0 + row) * DIM
                                          + c0 + i * 32 + cid * 4];
            h[i].x = f2bf(v.x); h[i].y = f2bf(v.y);
            h[i].z = f2bf(v.z); h[i].w = f2bf(v.w);
        }
#pragma unroll
        for (int i = 0; i < 4; ++i) {
            *(ushort4*)&xb[base + (long)(r0 + row) * DIM + c0 + i * 32 + cid * 4] = h[i];
            t[i][row][cid * 4 + 0] = h[i].x; t[i][row][cid * 4 + 1] = h[i].y;
            t[i][row][cid * 4 + 2] = h[i].z; t[i][row][cid * 4 + 3] = h[i].w;
        }
        __syncthreads();
#pragma unroll
        for (int i = 0; i < 4; ++i) {
            ushort4 o;
            o.x = t[i][cid * 4 + 0][row];
            o.y = t[i][cid * 4 + 1][row];
            o.z = t[i][cid * 4 + 2][row];
            o.w = t[i][cid * 4 + 3][row];
            *(ushort4*)&xTb[base + (long)(c0 + i * 32 + row) * SEQ + r0 + cid * 4] = o;
        }
        return;
    }

    // weights slice: y>>5 selects matrix, y&31 the 32-row band; x covers 128 cols
    const int wsel = blockIdx.y >> 5;        // 0=Wq 1=Wk 2=Wv 3=P
    const int r0 = (blockIdx.y & 31) * 32;
    const int c0 = blockIdx.x * 128;
    const float* src = (wsel == 0) ? Wq : (wsel == 1) ? Wk : (wsel == 2) ? Wv : P;

    ushort4 h[4];
#pragma unroll
    for (int i = 0; i < 4; ++i) {
        float4 v = *(const float4*)&src[(long)(r0 + row) * DIM + c0 + i * 32 + cid * 4];
        h[i].x = f2bf(v.x); h[i].y = f2bf(v.y);
        h[i].z = f2bf(v.z); h[i].w = f2bf(v.w);
    }

    if (wsel < 3) {
        unsigned short* dst = (wsel == 0) ? Wqb : (wsel == 1) ? Wkb : Wvb;
#pragma unroll
        for (int i = 0; i < 4; ++i)
            *(ushort4*)&dst[(long)(r0 + row) * DIM + c0 + i * 32 + cid * 4] = h[i];
        return;
    }
#pragma unroll
    for (int i = 0; i < 4; ++i) {
        t[i][row][cid * 4 + 0] = h[i].x; t[i][row][cid * 4 + 1] = h[i].y;
        t[i][row][cid * 4 + 2] = h[i].z; t[i][row][cid * 4 + 3] = h[i].w;
    }
    __syncthreads();
#pragma unroll
    for (int i = 0; i < 4; ++i) {
        ushort4 o;
        o.x = t[i][cid * 4 + 0][row];
        o.y = t[i][cid * 4 + 1][row];
        o.z = t[i][cid * 4 + 2][row];
        o.w = t[i][cid * 4 + 3][row];
        *(ushort4*)&Ptb[(long)(c0 + i * 32 + row) * DIM + r0 + cid * 4] = o;
    }
}

// ---------------------------------------------------------------------------
extern "C" void kernel_launch(void* const* d_in, const int* in_sizes, int n_in,
                              void* d_out, int out_size, void* d_ws, size_t ws_size,
                              hipStream_t stream)
{
    const float* x  = (const float*)d_in[0];
    const float* Wq = (const float*)d_in[1];
    const float* Wk = (const float*)d_in[2];
    const float* Wv = (const float*)d_in[3];
    const float* P  = (const float*)d_in[4];
    float* out = (float*)d_out;

    const long DD = (long)DIM * DIM;
    const long SD = (long)SEQ * DIM;

    // workspace layout (MiB offsets) — proven map; regA bf16 (36 MiB):
    //   [0,32) xb | [32,64) xTb -> Hb[32,40) Ntb[40,48)
    //   [64,72) Gb | [72,84) weights | [84,120) regA gram bf16 partials
    uint8_t* ws = (uint8_t*)d_ws;
    unsigned short* xb   = (unsigned short*)(ws);
    unsigned short* xTb  = (unsigned short*)(ws + (32ul << 20));
    unsigned short* Hb   = (unsigned short*)(ws + (32ul << 20));
    unsigned short* Ntb  = (unsigned short*)(ws + (40ul << 20));
    unsigned short* Gb   = (unsigned short*)(ws + (64ul << 20));
    unsigned short* Wqb  = (unsigned short*)(ws + (72ul << 20));
    unsigned short* Ptb  = (unsigned short*)(ws + (74ul << 20));
    unsigned short* Wkb  = (unsigned short*)(ws + (76ul << 20));
    unsigned short* Wvb  = (unsigned short*)(ws + (78ul << 20));
    unsigned short* Ub   = (unsigned short*)(ws + (80ul << 20));
    unsigned short* W2Tb = (unsigned short*)(ws + (82ul << 20));
    unsigned short* regA = (unsigned short*)(ws + (84ul << 20));

    const int split = 8;   // bf16 partials: 36 MiB

    // 1) x -> xb, xTb ; Wq/Wk/Wv -> bf16 ; P -> Pt   (single launch, 4x ILP)
    prep_all<<<dim3(DIM / 128, SEQ / 32, BATCH + 1), 256, 0, stream>>>(
        x, Wq, Wk, Wv, P, xb, xTb, Wqb, Wkb, Wvb, Ptb);

    // 2) G_b = xT_b @ xT_b^T — lower tiles, split-K bf16 partials;
    //    reduce also writes the symmetric mirror
    gemm_db<3, 128, true, false><<<dim3(36 * split * BATCH, 1, 1), 256, 0, stream>>>(
        xTb, xTb, regA, SEQ / split, split, SEQ, SEQ, DIM, SD, SD, 0);
    reduce_cast_tri<<<dim3(BATCH * 36 * 128 * 32 / 256), 256, 0, stream>>>(
        regA, Gb, split);

    // 3) {U, W2T} in one z=2 launch, split=1: U = Wq@Wk^T ; W2T = Pt@Wv^T
    gemm_db<1, 64, false, false><<<dim3(16, 8, 2), 256, 0, stream>>>(
        Wqb, Wkb, Ub, DIM, 1, DIM, DIM, DIM, DD, DD, DD);

    // 4) H_b = U @ G_b^T  (G symmetric)
    gemm_db<1, 64, false, false><<<dim3(16, 8, BATCH), 256, 0, stream>>>(
        Ub, Gb, Hb, DIM, 1, DIM, DIM, DIM, 0, DD, DD);

    // 5) Nt_b = W2T @ H_b^T + I   (residual folded in)
    gemm_db<1, 64, false, true><<<dim3(16, 8, BATCH), 256, 0, stream>>>(
        W2Tb, Hb, Ntb, DIM, 1, DIM, DIM, DIM, 0, DD, DD);

    // 6) out_b = xb_b @ Nt_b^T  (fp32 out, 256x256 2-cluster pipeline)
    gemm_db256<<<dim3(DIM / 256, SEQ / 256, BATCH), 512, 0, stream>>>(
        xb, Ntb, out, DIM, DIM, DIM, DIM, SD, DD, SD);
}

// Round 21
// 152.591 us; speedup vs baseline: 1.3028x; 1.0186x over previous
//
#include <hip/hip_runtime.h>
#include <hip/hip_bf16.h>
#include <stdint.h>

// out = x + x * [ (Wq Wk^T) * (x^T x) * (Wv P) ]  ==  x @ (I + N),  N = U G W2
// Final GEMM: 256x256 8-wave 2-cluster counted-vmcnt pipeline (best measured).
// Gram launch now ALSO runs the weights GEMMs (U, W2T) in its tail blocks
// (1152 gram + 128 weights = 1280 = 5 full rounds of 256 CUs).
// Prep: 4x-ILP strip version. Reduce: fused symmetric mirror.

#define BATCH 4
#define SEQ   4096
#define DIM   1024

#define TRI_SLICE 589824l       // 36 tiles * 128*128 elements per gram slice

typedef __bf16 bf16x8 __attribute__((ext_vector_type(8)));
typedef float f32x4 __attribute__((ext_vector_type(4)));

static __device__ __forceinline__ unsigned short f2bf(float f) {
    unsigned int u = __builtin_bit_cast(unsigned int, f);
    u += 0x7fff + ((u >> 16) & 1);              // RNE
    return (unsigned short)(u >> 16);
}
static __device__ __forceinline__ float bf2f(unsigned short h) {
    unsigned int u = (unsigned int)h << 16;
    return __builtin_bit_cast(float, u);
}

// ---------------------------------------------------------------------------
// 256x256-tile deep-pipelined bf16 MFMA GEMM: C = A @ Bt^T (fp32 out).
//  512 threads = 8 waves (2M x 4N), per-wave 128x64 output.
//  LDS [2][256][64] x2 = 128 KiB (1 block/CU). vmcnt(8) counted protocol.
//  Grid: (N/256, M/256, BATCH); flattened nwg % 8 == 0. K/64 >= 2.
// ---------------------------------------------------------------------------
__global__ __launch_bounds__(512)
void gemm_db256(const unsigned short* __restrict__ Ag,
                const unsigned short* __restrict__ Btg,
                float* __restrict__ Cg,
                int K, int lda, int ldbt, int ldc,
                long sA, long sBt, long sC)
{
    __shared__ unsigned short As[2][256][64];
    __shared__ unsigned short Bs[2][256][64];

    const int gx = gridDim.x, gy = gridDim.y;
    const int nwg = gx * gy * gridDim.z;
    int id = blockIdx.x + gx * (blockIdx.y + gy * blockIdx.z);
    id = (id & 7) * (nwg >> 3) + (id >> 3);

    const int bx = id % gx;
    const int rest = id / gx;
    const int by = rest % gy;
    const int b = rest / gy;
    const long i0 = (long)by * 256;
    const long j0 = (long)bx * 256;

    const unsigned short* A  = Ag  + (long)b * sA;
    const unsigned short* Bt = Btg + (long)b * sBt;

    const int tid  = threadIdx.x;
    const int lane = tid & 63;
    const int w    = tid >> 6;          // wave 0..7
    const int wr   = w >> 2;            // 0..1  (M half)
    const int wc   = w & 3;             // 0..3  (N quarter)
    const int lrow = lane >> 3;         // 0..7
    const int lcol = lane & 7;          // 0..7 (16B granule)
    const int fr   = lane & 15;
    const int kg   = lane >> 4;         // 0..3
    const int scol = (lcol ^ lrow) * 8; // pre-swizzled global source chunk

    f32x4 acc[8][4] = {};

    const int nt = K / 64;

    auto stage = [&](int t, int buf) {
        const long kk = (long)t * 64;
#pragma unroll
        for (int inst = 0; inst < 4; ++inst) {
            const int row = w * 32 + inst * 8;
            const unsigned short* srcA = A + (i0 + row + lrow) * lda + kk + scol;
            __builtin_amdgcn_global_load_lds(
                (const __attribute__((address_space(1))) void*)srcA,
                (__attribute__((address_space(3))) void*)&As[buf][row][0], 16, 0, 0);
            const unsigned short* srcB = Bt + (j0 + row + lrow) * ldbt + kk + scol;
            __builtin_amdgcn_global_load_lds(
                (const __attribute__((address_space(1))) void*)srcB,
                (__attribute__((address_space(3))) void*)&Bs[buf][row][0], 16, 0, 0);
        }
    };

    stage(0, 0);
    stage(1, 1);

    for (int t = 0; t < nt; ++t) {
        const int buf = t & 1;
        if (t < nt - 1) asm volatile("s_waitcnt vmcnt(8)" ::: "memory");
        else            asm volatile("s_waitcnt vmcnt(0)" ::: "memory");
        __builtin_amdgcn_s_barrier();
        asm volatile("" ::: "memory");

        // ---- cluster 0: reads (12 x b128) + MFMA (32)
        const int ch0 = (kg ^ (fr & 7)) * 8;
        bf16x8 af0[8], bf0[4];
#pragma unroll
        for (int m = 0; m < 8; ++m)
            af0[m] = *(const bf16x8*)&As[buf][wr * 128 + m * 16 + fr][ch0];
#pragma unroll
        for (int n = 0; n < 4; ++n)
            bf0[n] = *(const bf16x8*)&Bs[buf][wc * 64 + n * 16 + fr][ch0];
        __builtin_amdgcn_s_setprio(1);
#pragma unroll
        for (int m = 0; m < 8; ++m)
#pragma unroll
            for (int n = 0; n < 4; ++n)
                acc[m][n] = __builtin_amdgcn_mfma_f32_16x16x32_bf16(
                    af0[m], bf0[n], acc[m][n], 0, 0, 0);
        __builtin_amdgcn_s_setprio(0);

        // ---- cluster 1 reads
        const int ch1 = ((4 + kg) ^ (fr & 7)) * 8;
        bf16x8 af1[8], bf1[4];
#pragma unroll
        for (int m = 0; m < 8; ++m)
            af1[m] = *(const bf16x8*)&As[buf][wr * 128 + m * 16 + fr][ch1];
#pragma unroll
        for (int n = 0; n < 4; ++n)
            bf1[n] = *(const bf16x8*)&Bs[buf][wc * 64 + n * 16 + fr][ch1];

        asm volatile("s_waitcnt lgkmcnt(0)" ::: "memory");
        __builtin_amdgcn_sched_barrier(0);
        __builtin_amdgcn_s_barrier();          // all waves done reading buf
        asm volatile("" ::: "memory");

        if (t + 2 < nt) stage(t + 2, buf);     // loads fly under MFMA cluster 1
        __builtin_amdgcn_sched_barrier(0);

        __builtin_amdgcn_s_setprio(1);
#pragma unroll
        for (int m = 0; m < 8; ++m)
#pragma unroll
            for (int n = 0; n < 4; ++n)
                acc[m][n] = __builtin_amdgcn_mfma_f32_16x16x32_bf16(
                    af1[m], bf1[n], acc[m][n], 0, 0, 0);
        __builtin_amdgcn_s_setprio(0);
    }

    // ---- epilogue: C/D layout col = lane&15, row = (lane>>4)*4 + q
    float* C32 = Cg + (long)b * sC;
#pragma unroll
    for (int m = 0; m < 8; ++m) {
        const long rbase = i0 + wr * 128 + m * 16 + kg * 4;
#pragma unroll
        for (int n = 0; n < 4; ++n) {
            const long col = j0 + wc * 64 + n * 16 + fr;
#pragma unroll
            for (int q = 0; q < 4; ++q)
                C32[(rbase + q) * ldc + col] = acc[m][n][q];
        }
    }
}

// ---------------------------------------------------------------------------
// Merged gram + weights launch (1-D grid = NG + 128, NG = 36*split*BATCH):
//  id <  NG : gram slice — lower-triangle tile, K=K1, compact bf16 partial.
//  id >= NG : weights GEMM — wid>>6 selects {U = Wq@Wk^T ; W2T = Pt@Wv^T},
//             64 tiles each (128x128), K=DIM, bf16 out.
//  Proven BN=128 2-cluster counted-vmcnt(8) body; runtime nt/pointers.
// ---------------------------------------------------------------------------
__global__ __launch_bounds__(256)
void gram_w(const unsigned short* __restrict__ xT,
            unsigned short* __restrict__ part,
            const unsigned short* __restrict__ Wqb,
            const unsigned short* __restrict__ Wkb,
            const unsigned short* __restrict__ Ptb,
            const unsigned short* __restrict__ Wvb,
            unsigned short* __restrict__ Ub,
            unsigned short* __restrict__ W2Tb,
            int K1, int split, int NG)
{
    __shared__ unsigned short As[2][128][64];
    __shared__ unsigned short Bs[2][128][64];

    const long SD = (long)SEQ * DIM;
    const int nwg = gridDim.x;
    int id = blockIdx.x;
    id = (id & 7) * (nwg >> 3) + (id >> 3);

    const unsigned short *A, *Bt;
    unsigned short* C16 = nullptr;       // weights bf16 out
    unsigned short* Cp  = nullptr;       // gram compact partial out
    long i0, j0, lda, ldbt;
    int nt;

    if (id < NG) {
        const int z = id / 36;
        const int tlin = id % 36;
        int t = tlin, ti = 0;
        while (t > ti) { t -= ti + 1; ++ti; }
        i0 = (long)ti * 128;
        j0 = (long)t * 128;
        const int b = z / split;
        const long koff = (long)(z % split) * K1;
        A  = xT + (long)b * SD + koff;
        Bt = A;
        lda = ldbt = SEQ;
        nt = K1 / 64;
        Cp = part + (long)z * TRI_SLICE + (long)tlin * 16384;
    } else {
        const int wid = id - NG;
        const int z2 = wid >> 6;         // 0 = U, 1 = W2T
        const int t = wid & 63;
        i0 = (long)(t >> 3) * 128;
        j0 = (long)(t & 7) * 128;
        A   = z2 ? Ptb : Wqb;
        Bt  = z2 ? Wvb : Wkb;
        C16 = z2 ? W2Tb : Ub;
        lda = ldbt = DIM;
        nt = DIM / 64;                   // 16
    }

    const int tid  = threadIdx.x;
    const int lane = tid & 63;
    const int w    = tid >> 6;          // wave 0..3
    const int wr   = w >> 1, wc = w & 1;
    const int lrow = lane >> 3;         // 0..7
    const int lcol = lane & 7;          // 0..7 (16B granule)
    const int fr   = lane & 15;
    const int kg   = lane >> 4;         // 0..3
    const int scol = (lcol ^ lrow) * 8; // pre-swizzled global source chunk

    f32x4 acc[4][4] = {};

    auto stage = [&](int t, int buf) {
        const long kk = (long)t * 64;
#pragma unroll
        for (int inst = 0; inst < 4; ++inst) {
            const int row = w * 32 + inst * 8;
            const unsigned short* srcA = A + (i0 + row + lrow) * lda + kk + scol;
            __builtin_amdgcn_global_load_lds(
                (const __attribute__((address_space(1))) void*)srcA,
                (__attribute__((address_space(3))) void*)&As[buf][row][0], 16, 0, 0);
            const unsigned short* srcB = Bt + (j0 + row + lrow) * ldbt + kk + scol;
            __builtin_amdgcn_global_load_lds(
                (const __attribute__((address_space(1))) void*)srcB,
                (__attribute__((address_space(3))) void*)&Bs[buf][row][0], 16, 0, 0);
        }
    };

    stage(0, 0);
    stage(1, 1);

    for (int t = 0; t < nt; ++t) {
        const int buf = t & 1;
        if (t < nt - 1) asm volatile("s_waitcnt vmcnt(8)" ::: "memory");
        else            asm volatile("s_waitcnt vmcnt(0)" ::: "memory");
        __builtin_amdgcn_s_barrier();
        asm volatile("" ::: "memory");

        bf16x8 af0[4], bf0[4], af1[4], bf1[4];
        const int ch0 = (kg ^ (fr & 7)) * 8;
        const int ch1 = ((4 + kg) ^ (fr & 7)) * 8;
#pragma unroll
        for (int m = 0; m < 4; ++m)
            af0[m] = *(const bf16x8*)&As[buf][wr * 64 + m * 16 + fr][ch0];
#pragma unroll
        for (int n = 0; n < 4; ++n)
            bf0[n] = *(const bf16x8*)&Bs[buf][wc * 64 + n * 16 + fr][ch0];
#pragma unroll
        for (int m = 0; m < 4; ++m)
            af1[m] = *(const bf16x8*)&As[buf][wr * 64 + m * 16 + fr][ch1];
#pragma unroll
        for (int n = 0; n < 4; ++n)
            bf1[n] = *(const bf16x8*)&Bs[buf][wc * 64 + n * 16 + fr][ch1];

        __builtin_amdgcn_s_setprio(1);
#pragma unroll
        for (int m = 0; m < 4; ++m)
#pragma unroll
            for (int n = 0; n < 4; ++n)
                acc[m][n] = __builtin_amdgcn_mfma_f32_16x16x32_bf16(
                    af0[m], bf0[n], acc[m][n], 0, 0, 0);
        __builtin_amdgcn_s_setprio(0);

        asm volatile("s_waitcnt lgkmcnt(0)" ::: "memory");
        __builtin_amdgcn_sched_barrier(0);
        __builtin_amdgcn_s_barrier();
        asm volatile("" ::: "memory");

        if (t + 2 < nt) stage(t + 2, buf);
        __builtin_amdgcn_sched_barrier(0);

        __builtin_amdgcn_s_setprio(1);
#pragma unroll
        for (int m = 0; m < 4; ++m)
#pragma unroll
            for (int n = 0; n < 4; ++n)
                acc[m][n] = __builtin_amdgcn_mfma_f32_16x16x32_bf16(
                    af1[m], bf1[n], acc[m][n], 0, 0, 0);
        __builtin_amdgcn_s_setprio(0);
    }

    // epilogue: C/D layout col = lane&15, row = (lane>>4)*4 + q
    if (Cp) {
#pragma unroll
        for (int m = 0; m < 4; ++m) {
            const int lrb = wr * 64 + m * 16 + kg * 4;
#pragma unroll
            for (int n = 0; n < 4; ++n) {
                const int lc = wc * 64 + n * 16 + fr;
#pragma unroll
                for (int q = 0; q < 4; ++q)
                    Cp[(lrb + q) * 128 + lc] = f2bf(acc[m][n][q]);
            }
        }
        return;
    }
#pragma unroll
    for (int m = 0; m < 4; ++m) {
        const long rbase = i0 + wr * 64 + m * 16 + kg * 4;
#pragma unroll
        for (int n = 0; n < 4; ++n) {
            const long col = j0 + wc * 64 + n * 16 + fr;
#pragma unroll
            for (int q = 0; q < 4; ++q)
                C16[(rbase + q) * DIM + col] = f2bf(acc[m][n][q]);
        }
    }
}

// ---------------------------------------------------------------------------
// 128 x 64 deep-pipelined bf16 MFMA GEMM — D x D chain (H, Nt).
//  OUTMODE 1: bf16 out (+ optional identity add).
// ---------------------------------------------------------------------------
template<bool ADD_I>
__global__ __launch_bounds__(256)
void gemm_db(const unsigned short* __restrict__ Ag,
             const unsigned short* __restrict__ Btg,
             void* __restrict__ Cg,
             int K, int zdiv, int lda, int ldbt, int ldc,
             long sA, long sBt, long sC)
{
    constexpr int BN = 64, NF = 2;
    __shared__ unsigned short As[2][128][64];
    __shared__ unsigned short Bs[2][BN][64];

    const int gx = gridDim.x, gy = gridDim.y;
    const int nwg = gx * gy * gridDim.z;
    int id = blockIdx.x + gx * (blockIdx.y + gy * blockIdx.z);
    id = (id & 7) * (nwg >> 3) + (id >> 3);

    const int bx = id % gx;
    const int rest = id / gx;
    const int by = rest % gy;
    const int z = rest / gy;
    const long i0 = (long)by * 128;
    const long j0 = (long)bx * BN;
    const int b = z / zdiv;
    const long koff = (long)(z % zdiv) * K;

    const unsigned short* A  = Ag  + (long)b * sA  + koff;
    const unsigned short* Bt = Btg + (long)b * sBt + koff;

    const int tid  = threadIdx.x;
    const int lane = tid & 63;
    const int w    = tid >> 6;          // wave 0..3
    const int wr   = w >> 1, wc = w & 1;
    const int lrow = lane >> 3;
    const int lcol = lane & 7;
    const int fr   = lane & 15;
    const int kg   = lane >> 4;
    const int scol = (lcol ^ lrow) * 8;

    f32x4 acc[4][NF] = {};

    const int nt = K / 64;

    auto stage = [&](int t, int buf) {
        const long kk = (long)t * 64;
#pragma unroll
        for (int inst = 0; inst < 4; ++inst) {
            const int row = w * 32 + inst * 8;
            const unsigned short* srcA = A + (i0 + row + lrow) * lda + kk + scol;
            __builtin_amdgcn_global_load_lds(
                (const __attribute__((address_space(1))) void*)srcA,
                (__attribute__((address_space(3))) void*)&As[buf][row][0], 16, 0, 0);
        }
#pragma unroll
        for (int inst = 0; inst < NF; ++inst) {
            const int row = w * (8 * NF) + inst * 8;
            const unsigned short* srcB = Bt + (j0 + row + lrow) * ldbt + kk + scol;
            __builtin_amdgcn_global_load_lds(
                (const __attribute__((address_space(1))) void*)srcB,
                (__attribute__((address_space(3))) void*)&Bs[buf][row][0], 16, 0, 0);
        }
    };

    stage(0, 0);
    stage(1, 1);

    for (int t = 0; t < nt; ++t) {
        const int buf = t & 1;
        if (t < nt - 1) asm volatile("s_waitcnt vmcnt(6)" ::: "memory");
        else            asm volatile("s_waitcnt vmcnt(0)" ::: "memory");
        __builtin_amdgcn_s_barrier();
        asm volatile("" ::: "memory");

        bf16x8 af0[4], bf0[NF], af1[4], bf1[NF];
        const int ch0 = (kg ^ (fr & 7)) * 8;
        const int ch1 = ((4 + kg) ^ (fr & 7)) * 8;
#pragma unroll
        for (int m = 0; m < 4; ++m)
            af0[m] = *(const bf16x8*)&As[buf][wr * 64 + m * 16 + fr][ch0];
#pragma unroll
        for (int n = 0; n < NF; ++n)
            bf0[n] = *(const bf16x8*)&Bs[buf][wc * (BN / 2) + n * 16 + fr][ch0];
#pragma unroll
        for (int m = 0; m < 4; ++m)
            af1[m] = *(const bf16x8*)&As[buf][wr * 64 + m * 16 + fr][ch1];
#pragma unroll
        for (int n = 0; n < NF; ++n)
            bf1[n] = *(const bf16x8*)&Bs[buf][wc * (BN / 2) + n * 16 + fr][ch1];

        __builtin_amdgcn_s_setprio(1);
#pragma unroll
        for (int m = 0; m < 4; ++m)
#pragma unroll
            for (int n = 0; n < NF; ++n)
                acc[m][n] = __builtin_amdgcn_mfma_f32_16x16x32_bf16(
                    af0[m], bf0[n], acc[m][n], 0, 0, 0);
        __builtin_amdgcn_s_setprio(0);

        asm volatile("s_waitcnt lgkmcnt(0)" ::: "memory");
        __builtin_amdgcn_sched_barrier(0);
        __builtin_amdgcn_s_barrier();
        asm volatile("" ::: "memory");

        if (t + 2 < nt) stage(t + 2, buf);
        __builtin_amdgcn_sched_barrier(0);

        __builtin_amdgcn_s_setprio(1);
#pragma unroll
        for (int m = 0; m < 4; ++m)
#pragma unroll
            for (int n = 0; n < NF; ++n)
                acc[m][n] = __builtin_amdgcn_mfma_f32_16x16x32_bf16(
                    af1[m], bf1[n], acc[m][n], 0, 0, 0);
        __builtin_amdgcn_s_setprio(0);
    }

    unsigned short* C16 = (unsigned short*)Cg + (long)b * sC;
#pragma unroll
    for (int m = 0; m < 4; ++m) {
        const long rbase = i0 + wr * 64 + m * 16 + kg * 4;
#pragma unroll
        for (int n = 0; n < NF; ++n) {
            const long col = j0 + wc * (BN / 2) + n * 16 + fr;
#pragma unroll
            for (int q = 0; q < 4; ++q) {
                const long r = rbase + q;
                float v = acc[m][n][q];
                if (ADD_I && r == col) v += 1.0f;
                C16[r * ldc + col] = f2bf(v);
            }
        }
    }
}

// ---------------------------------------------------------------------------
// Reduce gram split-K BF16 compact partials -> bf16 G (lower tiles), AND
// write the strict-upper mirror (transposed strip via LDS).
// ---------------------------------------------------------------------------
__global__ __launch_bounds__(256)
void reduce_cast_tri(const unsigned short* __restrict__ part,
                     unsigned short* __restrict__ outG, int split)
{
    __shared__ unsigned short s[8][132];
    const long DD = (long)DIM * DIM;
    int id = blockIdx.x * 256 + threadIdx.x;
    const int b  = id / 147456;          // 36*128*32
    int rem      = id % 147456;
    const int tlin = rem / 4096;
    const int rr = rem % 4096;
    const int r  = rr >> 5;
    const int c4 = rr & 31;
    int t = tlin, ti = 0;
    while (t > ti) { t -= ti + 1; ++ti; }
    const long off = (long)tlin * 16384 + r * 128 + c4 * 4;

    float4 sum = make_float4(0.f, 0.f, 0.f, 0.f);
    for (int sp = 0; sp < split; ++sp) {
        ushort4 v = *(const ushort4*)&part[(long)(b * split + sp) * TRI_SLICE + off];
        sum.x += bf2f(v.x); sum.y += bf2f(v.y); sum.z += bf2f(v.z); sum.w += bf2f(v.w);
    }
    ushort4 o;
    o.x = f2bf(sum.x); o.y = f2bf(sum.y); o.z = f2bf(sum.z); o.w = f2bf(sum.w);
    *(ushort4*)&outG[b * DD + ((long)ti * 128 + r) * DIM + (long)t * 128 + c4 * 4] = o;

    if (t == ti) return;                 // diagonal tile: already complete

    const int rl = r & 7;
    s[rl][c4 * 4 + 0] = o.x; s[rl][c4 * 4 + 1] = o.y;
    s[rl][c4 * 4 + 2] = o.z; s[rl][c4 * 4 + 3] = o.w;
    __syncthreads();

    const int r0 = r & ~7;
    const int co = threadIdx.x >> 1;
    const int hf = threadIdx.x & 1;
    ushort4 m;
    m.x = s[hf * 4 + 0][co]; m.y = s[hf * 4 + 1][co];
    m.z = s[hf * 4 + 2][co]; m.w = s[hf * 4 + 3][co];
    *(ushort4*)&outG[b * DD + ((long)t * 128 + co) * DIM
                     + (long)ti * 128 + r0 + hf * 4] = m;
}

// ---------------------------------------------------------------------------
// Unified prep, 4x ILP: each block covers a 32-row x 128-col strip.
// z < BATCH: x batch z -> xb + xTb.  z == BATCH: weights cast / P transpose.
// Grid (DIM/128, SEQ/32, BATCH+1).
// ---------------------------------------------------------------------------
__global__ __launch_bounds__(256)
void prep_all(const float* __restrict__ x,
              const float* __restrict__ Wq, const float* __restrict__ Wk,
              const float* __restrict__ Wv, const float* __restrict__ P,
              unsigned short* __restrict__ xb, unsigned short* __restrict__ xTb,
              unsigned short* __restrict__ Wqb, unsigned short* __restrict__ Wkb,
              unsigned short* __restrict__ Wvb, unsigned short* __restrict__ Ptb)
{
    __shared__ unsigned short t[4][32][33];
    const int z = blockIdx.z;
    const int row = threadIdx.x >> 3;
    const int cid = threadIdx.x & 7;

    if (z < BATCH) {
        const long base = (long)z * SEQ * DIM;
        const int r0 = blockIdx.y * 32;      // over S
        const int c0 = blockIdx.x * 128;     // over D
        ushort4 h[4];
#pragma unroll
        for (int i = 0; i < 4; ++i) {
            float4 v = *(const float4*)&x[base + (long)(r0 + row) * DIM
                                          + c0 + i * 32 + cid * 4];
            h[i].x = f2bf(v.x); h[i].y = f2bf(v.y);
            h[i].z = f2bf(v.z); h[i].w = f2bf(v.w);
        }
#pragma unroll
        for (int i = 0; i < 4; ++i) {
            *(ushort4*)&xb[base + (long)(r0 + row) * DIM + c0 + i * 32 + cid * 4] = h[i];
            t[i][row][cid * 4 + 0] = h[i].x; t[i][row][cid * 4 + 1] = h[i].y;
            t[i][row][cid * 4 + 2] = h[i].z; t[i][row][cid * 4 + 3] = h[i].w;
        }
        __syncthreads();
#pragma unroll
        for (int i = 0; i < 4; ++i) {
            ushort4 o;
            o.x = t[i][cid * 4 + 0][row];
            o.y = t[i][cid * 4 + 1][row];
            o.z = t[i][cid * 4 + 2][row];
            o.w = t[i][cid * 4 + 3][row];
            *(ushort4*)&xTb[base + (long)(c0 + i * 32 + row) * SEQ + r0 + cid * 4] = o;
        }
        return;
    }

    const int wsel = blockIdx.y >> 5;        // 0=Wq 1=Wk 2=Wv 3=P
    const int r0 = (blockIdx.y & 31) * 32;
    const int c0 = blockIdx.x * 128;
    const float* src = (wsel == 0) ? Wq : (wsel == 1) ? Wk : (wsel == 2) ? Wv : P;

    ushort4 h[4];
#pragma unroll
    for (int i = 0; i < 4; ++i) {
        float4 v = *(const float4*)&src[(long)(r0 + row) * DIM + c0 + i * 32 + cid * 4];
        h[i].x = f2bf(v.x); h[i].y = f2bf(v.y);
        h[i].z = f2bf(v.z); h[i].w = f2bf(v.w);
    }

    if (wsel < 3) {
        unsigned short* dst = (wsel == 0) ? Wqb : (wsel == 1) ? Wkb : Wvb;
#pragma unroll
        for (int i = 0; i < 4; ++i)
            *(ushort4*)&dst[(long)(r0 + row) * DIM + c0 + i * 32 + cid * 4] = h[i];
        return;
    }
#pragma unroll
    for (int i = 0; i < 4; ++i) {
        t[i][row][cid * 4 + 0] = h[i].x; t[i][row][cid * 4 + 1] = h[i].y;
        t[i][row][cid * 4 + 2] = h[i].z; t[i][row][cid * 4 + 3] = h[i].w;
    }
    __syncthreads();
#pragma unroll
    for (int i = 0; i < 4; ++i) {
        ushort4 o;
        o.x = t[i][cid * 4 + 0][row];
        o.y = t[i][cid * 4 + 1][row];
        o.z = t[i][cid * 4 + 2][row];
        o.w = t[i][cid * 4 + 3][row];
        *(ushort4*)&Ptb[(long)(c0 + i * 32 + row) * DIM + r0 + cid * 4] = o;
    }
}

// ---------------------------------------------------------------------------
extern "C" void kernel_launch(void* const* d_in, const int* in_sizes, int n_in,
                              void* d_out, int out_size, void* d_ws, size_t ws_size,
                              hipStream_t stream)
{
    const float* x  = (const float*)d_in[0];
    const float* Wq = (const float*)d_in[1];
    const float* Wk = (const float*)d_in[2];
    const float* Wv = (const float*)d_in[3];
    const float* P  = (const float*)d_in[4];
    float* out = (float*)d_out;

    const long DD = (long)DIM * DIM;
    const long SD = (long)SEQ * DIM;

    // workspace layout (MiB offsets) — proven map; regA bf16 (36 MiB):
    //   [0,32) xb | [32,64) xTb -> Hb[32,40) Ntb[40,48)
    //   [64,72) Gb | [72,84) weights | [84,120) regA gram bf16 partials
    uint8_t* ws = (uint8_t*)d_ws;
    unsigned short* xb   = (unsigned short*)(ws);
    unsigned short* xTb  = (unsigned short*)(ws + (32ul << 20));
    unsigned short* Hb   = (unsigned short*)(ws + (32ul << 20));
    unsigned short* Ntb  = (unsigned short*)(ws + (40ul << 20));
    unsigned short* Gb   = (unsigned short*)(ws + (64ul << 20));
    unsigned short* Wqb  = (unsigned short*)(ws + (72ul << 20));
    unsigned short* Ptb  = (unsigned short*)(ws + (74ul << 20));
    unsigned short* Wkb  = (unsigned short*)(ws + (76ul << 20));
    unsigned short* Wvb  = (unsigned short*)(ws + (78ul << 20));
    unsigned short* Ub   = (unsigned short*)(ws + (80ul << 20));
    unsigned short* W2Tb = (unsigned short*)(ws + (82ul << 20));
    unsigned short* regA = (unsigned short*)(ws + (84ul << 20));

    const int split = 8;                 // bf16 partials: 36 MiB
    const int NG = 36 * split * BATCH;   // 1152 gram blocks

    // 1) x -> xb, xTb ; Wq/Wk/Wv -> bf16 ; P -> Pt   (single launch, 4x ILP)
    prep_all<<<dim3(DIM / 128, SEQ / 32, BATCH + 1), 256, 0, stream>>>(
        x, Wq, Wk, Wv, P, xb, xTb, Wqb, Wkb, Wvb, Ptb);

    // 2) merged: gram lower-tile bf16 partials + weights GEMMs {U, W2T}
    //    (1152 + 128 = 1280 blocks = 5 full rounds of 256 CUs)
    gram_w<<<dim3(NG + 128), 256, 0, stream>>>(
        xTb, regA, Wqb, Wkb, Ptb, Wvb, Ub, W2Tb, SEQ / split, split, NG);
    reduce_cast_tri<<<dim3(BATCH * 36 * 128 * 32 / 256), 256, 0, stream>>>(
        regA, Gb, split);

    // 3) H_b = U @ G_b^T  (G symmetric)
    gemm_db<false><<<dim3(16, 8, BATCH), 256, 0, stream>>>(
        Ub, Gb, Hb, DIM, 1, DIM, DIM, DIM, 0, DD, DD);

    // 4) Nt_b = W2T @ H_b^T + I   (residual folded in)
    gemm_db<true><<<dim3(16, 8, BATCH), 256, 0, stream>>>(
        W2Tb, Hb, Ntb, DIM, 1, DIM, DIM, DIM, 0, DD, DD);

    // 5) out_b = xb_b @ Nt_b^T  (fp32 out, 256x256 2-cluster pipeline)
    gemm_db256<<<dim3(DIM / 256, SEQ / 256, BATCH), 512, 0, stream>>>(
        xb, Ntb, out, DIM, DIM, DIM, DIM, SD, DD, SD);
}

// Round 22
// 138.508 us; speedup vs baseline: 1.4353x; 1.1017x over previous
//
#include <hip/hip_runtime.h>
#include <hip/hip_bf16.h>
#include <stdint.h>

// out = x + x * [ (Wq Wk^T) * (x^T x) * (Wv P) ]  ==  x @ (I + N),  N = U G W2
// Final GEMM: 256x256 8-wave 2-cluster counted-vmcnt pipeline (best measured).
// Merged gram+weights launch with split=4 -> ALL blocks nt=16 (uniform
// durations, halved fill/drain overhead, halved partial traffic).
// Prep: 4x-ILP strip version. Reduce: fused symmetric mirror.

#define BATCH 4
#define SEQ   4096
#define DIM   1024

#define TRI_SLICE 589824l       // 36 tiles * 128*128 elements per gram slice

typedef __bf16 bf16x8 __attribute__((ext_vector_type(8)));
typedef float f32x4 __attribute__((ext_vector_type(4)));

static __device__ __forceinline__ unsigned short f2bf(float f) {
    unsigned int u = __builtin_bit_cast(unsigned int, f);
    u += 0x7fff + ((u >> 16) & 1);              // RNE
    return (unsigned short)(u >> 16);
}
static __device__ __forceinline__ float bf2f(unsigned short h) {
    unsigned int u = (unsigned int)h << 16;
    return __builtin_bit_cast(float, u);
}

// ---------------------------------------------------------------------------
// 256x256-tile deep-pipelined bf16 MFMA GEMM: C = A @ Bt^T (fp32 out).
//  512 threads = 8 waves (2M x 4N), per-wave 128x64 output.
//  LDS [2][256][64] x2 = 128 KiB (1 block/CU). vmcnt(8) counted protocol.
//  Grid: (N/256, M/256, BATCH); flattened nwg % 8 == 0. K/64 >= 2.
// ---------------------------------------------------------------------------
__global__ __launch_bounds__(512)
void gemm_db256(const unsigned short* __restrict__ Ag,
                const unsigned short* __restrict__ Btg,
                float* __restrict__ Cg,
                int K, int lda, int ldbt, int ldc,
                long sA, long sBt, long sC)
{
    __shared__ unsigned short As[2][256][64];
    __shared__ unsigned short Bs[2][256][64];

    const int gx = gridDim.x, gy = gridDim.y;
    const int nwg = gx * gy * gridDim.z;
    int id = blockIdx.x + gx * (blockIdx.y + gy * blockIdx.z);
    id = (id & 7) * (nwg >> 3) + (id >> 3);

    const int bx = id % gx;
    const int rest = id / gx;
    const int by = rest % gy;
    const int b = rest / gy;
    const long i0 = (long)by * 256;
    const long j0 = (long)bx * 256;

    const unsigned short* A  = Ag  + (long)b * sA;
    const unsigned short* Bt = Btg + (long)b * sBt;

    const int tid  = threadIdx.x;
    const int lane = tid & 63;
    const int w    = tid >> 6;          // wave 0..7
    const int wr   = w >> 2;            // 0..1  (M half)
    const int wc   = w & 3;             // 0..3  (N quarter)
    const int lrow = lane >> 3;         // 0..7
    const int lcol = lane & 7;          // 0..7 (16B granule)
    const int fr   = lane & 15;
    const int kg   = lane >> 4;         // 0..3
    const int scol = (lcol ^ lrow) * 8; // pre-swizzled global source chunk

    f32x4 acc[8][4] = {};

    const int nt = K / 64;

    auto stage = [&](int t, int buf) {
        const long kk = (long)t * 64;
#pragma unroll
        for (int inst = 0; inst < 4; ++inst) {
            const int row = w * 32 + inst * 8;
            const unsigned short* srcA = A + (i0 + row + lrow) * lda + kk + scol;
            __builtin_amdgcn_global_load_lds(
                (const __attribute__((address_space(1))) void*)srcA,
                (__attribute__((address_space(3))) void*)&As[buf][row][0], 16, 0, 0);
            const unsigned short* srcB = Bt + (j0 + row + lrow) * ldbt + kk + scol;
            __builtin_amdgcn_global_load_lds(
                (const __attribute__((address_space(1))) void*)srcB,
                (__attribute__((address_space(3))) void*)&Bs[buf][row][0], 16, 0, 0);
        }
    };

    stage(0, 0);
    stage(1, 1);

    for (int t = 0; t < nt; ++t) {
        const int buf = t & 1;
        if (t < nt - 1) asm volatile("s_waitcnt vmcnt(8)" ::: "memory");
        else            asm volatile("s_waitcnt vmcnt(0)" ::: "memory");
        __builtin_amdgcn_s_barrier();
        asm volatile("" ::: "memory");

        // ---- cluster 0: reads (12 x b128) + MFMA (32)
        const int ch0 = (kg ^ (fr & 7)) * 8;
        bf16x8 af0[8], bf0[4];
#pragma unroll
        for (int m = 0; m < 8; ++m)
            af0[m] = *(const bf16x8*)&As[buf][wr * 128 + m * 16 + fr][ch0];
#pragma unroll
        for (int n = 0; n < 4; ++n)
            bf0[n] = *(const bf16x8*)&Bs[buf][wc * 64 + n * 16 + fr][ch0];
        __builtin_amdgcn_s_setprio(1);
#pragma unroll
        for (int m = 0; m < 8; ++m)
#pragma unroll
            for (int n = 0; n < 4; ++n)
                acc[m][n] = __builtin_amdgcn_mfma_f32_16x16x32_bf16(
                    af0[m], bf0[n], acc[m][n], 0, 0, 0);
        __builtin_amdgcn_s_setprio(0);

        // ---- cluster 1 reads
        const int ch1 = ((4 + kg) ^ (fr & 7)) * 8;
        bf16x8 af1[8], bf1[4];
#pragma unroll
        for (int m = 0; m < 8; ++m)
            af1[m] = *(const bf16x8*)&As[buf][wr * 128 + m * 16 + fr][ch1];
#pragma unroll
        for (int n = 0; n < 4; ++n)
            bf1[n] = *(const bf16x8*)&Bs[buf][wc * 64 + n * 16 + fr][ch1];

        asm volatile("s_waitcnt lgkmcnt(0)" ::: "memory");
        __builtin_amdgcn_sched_barrier(0);
        __builtin_amdgcn_s_barrier();          // all waves done reading buf
        asm volatile("" ::: "memory");

        if (t + 2 < nt) stage(t + 2, buf);     // loads fly under MFMA cluster 1
        __builtin_amdgcn_sched_barrier(0);

        __builtin_amdgcn_s_setprio(1);
#pragma unroll
        for (int m = 0; m < 8; ++m)
#pragma unroll
            for (int n = 0; n < 4; ++n)
                acc[m][n] = __builtin_amdgcn_mfma_f32_16x16x32_bf16(
                    af1[m], bf1[n], acc[m][n], 0, 0, 0);
        __builtin_amdgcn_s_setprio(0);
    }

    // ---- epilogue: C/D layout col = lane&15, row = (lane>>4)*4 + q
    float* C32 = Cg + (long)b * sC;
#pragma unroll
    for (int m = 0; m < 8; ++m) {
        const long rbase = i0 + wr * 128 + m * 16 + kg * 4;
#pragma unroll
        for (int n = 0; n < 4; ++n) {
            const long col = j0 + wc * 64 + n * 16 + fr;
#pragma unroll
            for (int q = 0; q < 4; ++q)
                C32[(rbase + q) * ldc + col] = acc[m][n][q];
        }
    }
}

// ---------------------------------------------------------------------------
// Merged gram + weights launch (1-D grid = NG + 128, NG = 36*split*BATCH):
//  id <  NG : gram slice — lower-triangle tile, K=K1, compact bf16 partial.
//  id >= NG : weights GEMM — wid>>6 selects {U = Wq@Wk^T ; W2T = Pt@Wv^T},
//             64 tiles each (128x128), K=DIM, bf16 out.
//  With split=4: K1=1024 -> nt=16 for ALL blocks (uniform durations).
// ---------------------------------------------------------------------------
__global__ __launch_bounds__(256)
void gram_w(const unsigned short* __restrict__ xT,
            unsigned short* __restrict__ part,
            const unsigned short* __restrict__ Wqb,
            const unsigned short* __restrict__ Wkb,
            const unsigned short* __restrict__ Ptb,
            const unsigned short* __restrict__ Wvb,
            unsigned short* __restrict__ Ub,
            unsigned short* __restrict__ W2Tb,
            int K1, int split, int NG)
{
    __shared__ unsigned short As[2][128][64];
    __shared__ unsigned short Bs[2][128][64];

    const long SD = (long)SEQ * DIM;
    const int nwg = gridDim.x;
    int id = blockIdx.x;
    id = (id & 7) * (nwg >> 3) + (id >> 3);

    const unsigned short *A, *Bt;
    unsigned short* C16 = nullptr;       // weights bf16 out
    unsigned short* Cp  = nullptr;       // gram compact partial out
    long i0, j0, lda, ldbt;
    int nt;

    if (id < NG) {
        const int z = id / 36;
        const int tlin = id % 36;
        int t = tlin, ti = 0;
        while (t > ti) { t -= ti + 1; ++ti; }
        i0 = (long)ti * 128;
        j0 = (long)t * 128;
        const int b = z / split;
        const long koff = (long)(z % split) * K1;
        A  = xT + (long)b * SD + koff;
        Bt = A;
        lda = ldbt = SEQ;
        nt = K1 / 64;
        Cp = part + (long)z * TRI_SLICE + (long)tlin * 16384;
    } else {
        const int wid = id - NG;
        const int z2 = wid >> 6;         // 0 = U, 1 = W2T
        const int t = wid & 63;
        i0 = (long)(t >> 3) * 128;
        j0 = (long)(t & 7) * 128;
        A   = z2 ? Ptb : Wqb;
        Bt  = z2 ? Wvb : Wkb;
        C16 = z2 ? W2Tb : Ub;
        lda = ldbt = DIM;
        nt = DIM / 64;                   // 16
    }

    const int tid  = threadIdx.x;
    const int lane = tid & 63;
    const int w    = tid >> 6;          // wave 0..3
    const int wr   = w >> 1, wc = w & 1;
    const int lrow = lane >> 3;         // 0..7
    const int lcol = lane & 7;          // 0..7 (16B granule)
    const int fr   = lane & 15;
    const int kg   = lane >> 4;         // 0..3
    const int scol = (lcol ^ lrow) * 8; // pre-swizzled global source chunk

    f32x4 acc[4][4] = {};

    auto stage = [&](int t, int buf) {
        const long kk = (long)t * 64;
#pragma unroll
        for (int inst = 0; inst < 4; ++inst) {
            const int row = w * 32 + inst * 8;
            const unsigned short* srcA = A + (i0 + row + lrow) * lda + kk + scol;
            __builtin_amdgcn_global_load_lds(
                (const __attribute__((address_space(1))) void*)srcA,
                (__attribute__((address_space(3))) void*)&As[buf][row][0], 16, 0, 0);
            const unsigned short* srcB = Bt + (j0 + row + lrow) * ldbt + kk + scol;
            __builtin_amdgcn_global_load_lds(
                (const __attribute__((address_space(1))) void*)srcB,
                (__attribute__((address_space(3))) void*)&Bs[buf][row][0], 16, 0, 0);
        }
    };

    stage(0, 0);
    stage(1, 1);

    for (int t = 0; t < nt; ++t) {
        const int buf = t & 1;
        if (t < nt - 1) asm volatile("s_waitcnt vmcnt(8)" ::: "memory");
        else            asm volatile("s_waitcnt vmcnt(0)" ::: "memory");
        __builtin_amdgcn_s_barrier();
        asm volatile("" ::: "memory");

        bf16x8 af0[4], bf0[4], af1[4], bf1[4];
        const int ch0 = (kg ^ (fr & 7)) * 8;
        const int ch1 = ((4 + kg) ^ (fr & 7)) * 8;
#pragma unroll
        for (int m = 0; m < 4; ++m)
            af0[m] = *(const bf16x8*)&As[buf][wr * 64 + m * 16 + fr][ch0];
#pragma unroll
        for (int n = 0; n < 4; ++n)
            bf0[n] = *(const bf16x8*)&Bs[buf][wc * 64 + n * 16 + fr][ch0];
#pragma unroll
        for (int m = 0; m < 4; ++m)
            af1[m] = *(const bf16x8*)&As[buf][wr * 64 + m * 16 + fr][ch1];
#pragma unroll
        for (int n = 0; n < 4; ++n)
            bf1[n] = *(const bf16x8*)&Bs[buf][wc * 64 + n * 16 + fr][ch1];

        __builtin_amdgcn_s_setprio(1);
#pragma unroll
        for (int m = 0; m < 4; ++m)
#pragma unroll
            for (int n = 0; n < 4; ++n)
                acc[m][n] = __builtin_amdgcn_mfma_f32_16x16x32_bf16(
                    af0[m], bf0[n], acc[m][n], 0, 0, 0);
        __builtin_amdgcn_s_setprio(0);

        asm volatile("s_waitcnt lgkmcnt(0)" ::: "memory");
        __builtin_amdgcn_sched_barrier(0);
        __builtin_amdgcn_s_barrier();
        asm volatile("" ::: "memory");

        if (t + 2 < nt) stage(t + 2, buf);
        __builtin_amdgcn_sched_barrier(0);

        __builtin_amdgcn_s_setprio(1);
#pragma unroll
        for (int m = 0; m < 4; ++m)
#pragma unroll
            for (int n = 0; n < 4; ++n)
                acc[m][n] = __builtin_amdgcn_mfma_f32_16x16x32_bf16(
                    af1[m], bf1[n], acc[m][n], 0, 0, 0);
        __builtin_amdgcn_s_setprio(0);
    }

    // epilogue: C/D layout col = lane&15, row = (lane>>4)*4 + q
    if (Cp) {
#pragma unroll
        for (int m = 0; m < 4; ++m) {
            const int lrb = wr * 64 + m * 16 + kg * 4;
#pragma unroll
            for (int n = 0; n < 4; ++n) {
                const int lc = wc * 64 + n * 16 + fr;
#pragma unroll
                for (int q = 0; q < 4; ++q)
                    Cp[(lrb + q) * 128 + lc] = f2bf(acc[m][n][q]);
            }
        }
        return;
    }
#pragma unroll
    for (int m = 0; m < 4; ++m) {
        const long rbase = i0 + wr * 64 + m * 16 + kg * 4;
#pragma unroll
        for (int n = 0; n < 4; ++n) {
            const long col = j0 + wc * 64 + n * 16 + fr;
#pragma unroll
            for (int q = 0; q < 4; ++q)
                C16[(rbase + q) * DIM + col] = f2bf(acc[m][n][q]);
        }
    }
}

// ---------------------------------------------------------------------------
// 128 x 64 deep-pipelined bf16 MFMA GEMM — D x D chain (H, Nt).
//  bf16 out (+ optional identity add).
// ---------------------------------------------------------------------------
template<bool ADD_I>
__global__ __launch_bounds__(256)
void gemm_db(const unsigned short* __restrict__ Ag,
             const unsigned short* __restrict__ Btg,
             void* __restrict__ Cg,
             int K, int zdiv, int lda, int ldbt, int ldc,
             long sA, long sBt, long sC)
{
    constexpr int BN = 64, NF = 2;
    __shared__ unsigned short As[2][128][64];
    __shared__ unsigned short Bs[2][BN][64];

    const int gx = gridDim.x, gy = gridDim.y;
    const int nwg = gx * gy * gridDim.z;
    int id = blockIdx.x + gx * (blockIdx.y + gy * blockIdx.z);
    id = (id & 7) * (nwg >> 3) + (id >> 3);

    const int bx = id % gx;
    const int rest = id / gx;
    const int by = rest % gy;
    const int z = rest / gy;
    const long i0 = (long)by * 128;
    const long j0 = (long)bx * BN;
    const int b = z / zdiv;
    const long koff = (long)(z % zdiv) * K;

    const unsigned short* A  = Ag  + (long)b * sA  + koff;
    const unsigned short* Bt = Btg + (long)b * sBt + koff;

    const int tid  = threadIdx.x;
    const int lane = tid & 63;
    const int w    = tid >> 6;          // wave 0..3
    const int wr   = w >> 1, wc = w & 1;
    const int lrow = lane >> 3;
    const int lcol = lane & 7;
    const int fr   = lane & 15;
    const int kg   = lane >> 4;
    const int scol = (lcol ^ lrow) * 8;

    f32x4 acc[4][NF] = {};

    const int nt = K / 64;

    auto stage = [&](int t, int buf) {
        const long kk = (long)t * 64;
#pragma unroll
        for (int inst = 0; inst < 4; ++inst) {
            const int row = w * 32 + inst * 8;
            const unsigned short* srcA = A + (i0 + row + lrow) * lda + kk + scol;
            __builtin_amdgcn_global_load_lds(
                (const __attribute__((address_space(1))) void*)srcA,
                (__attribute__((address_space(3))) void*)&As[buf][row][0], 16, 0, 0);
        }
#pragma unroll
        for (int inst = 0; inst < NF; ++inst) {
            const int row = w * (8 * NF) + inst * 8;
            const unsigned short* srcB = Bt + (j0 + row + lrow) * ldbt + kk + scol;
            __builtin_amdgcn_global_load_lds(
                (const __attribute__((address_space(1))) void*)srcB,
                (__attribute__((address_space(3))) void*)&Bs[buf][row][0], 16, 0, 0);
        }
    };

    stage(0, 0);
    stage(1, 1);

    for (int t = 0; t < nt; ++t) {
        const int buf = t & 1;
        if (t < nt - 1) asm volatile("s_waitcnt vmcnt(6)" ::: "memory");
        else            asm volatile("s_waitcnt vmcnt(0)" ::: "memory");
        __builtin_amdgcn_s_barrier();
        asm volatile("" ::: "memory");

        bf16x8 af0[4], bf0[NF], af1[4], bf1[NF];
        const int ch0 = (kg ^ (fr & 7)) * 8;
        const int ch1 = ((4 + kg) ^ (fr & 7)) * 8;
#pragma unroll
        for (int m = 0; m < 4; ++m)
            af0[m] = *(const bf16x8*)&As[buf][wr * 64 + m * 16 + fr][ch0];
#pragma unroll
        for (int n = 0; n < NF; ++n)
            bf0[n] = *(const bf16x8*)&Bs[buf][wc * (BN / 2) + n * 16 + fr][ch0];
#pragma unroll
        for (int m = 0; m < 4; ++m)
            af1[m] = *(const bf16x8*)&As[buf][wr * 64 + m * 16 + fr][ch1];
#pragma unroll
        for (int n = 0; n < NF; ++n)
            bf1[n] = *(const bf16x8*)&Bs[buf][wc * (BN / 2) + n * 16 + fr][ch1];

        __builtin_amdgcn_s_setprio(1);
#pragma unroll
        for (int m = 0; m < 4; ++m)
#pragma unroll
            for (int n = 0; n < NF; ++n)
                acc[m][n] = __builtin_amdgcn_mfma_f32_16x16x32_bf16(
                    af0[m], bf0[n], acc[m][n], 0, 0, 0);
        __builtin_amdgcn_s_setprio(0);

        asm volatile("s_waitcnt lgkmcnt(0)" ::: "memory");
        __builtin_amdgcn_sched_barrier(0);
        __builtin_amdgcn_s_barrier();
        asm volatile("" ::: "memory");

        if (t + 2 < nt) stage(t + 2, buf);
        __builtin_amdgcn_sched_barrier(0);

        __builtin_amdgcn_s_setprio(1);
#pragma unroll
        for (int m = 0; m < 4; ++m)
#pragma unroll
            for (int n = 0; n < NF; ++n)
                acc[m][n] = __builtin_amdgcn_mfma_f32_16x16x32_bf16(
                    af1[m], bf1[n], acc[m][n], 0, 0, 0);
        __builtin_amdgcn_s_setprio(0);
    }

    unsigned short* C16 = (unsigned short*)Cg + (long)b * sC;
#pragma unroll
    for (int m = 0; m < 4; ++m) {
        const long rbase = i0 + wr * 64 + m * 16 + kg * 4;
#pragma unroll
        for (int n = 0; n < NF; ++n) {
            const long col = j0 + wc * (BN / 2) + n * 16 + fr;
#pragma unroll
            for (int q = 0; q < 4; ++q) {
                const long r = rbase + q;
                float v = acc[m][n][q];
                if (ADD_I && r == col) v += 1.0f;
                C16[r * ldc + col] = f2bf(v);
            }
        }
    }
}

// ---------------------------------------------------------------------------
// Reduce gram split-K BF16 compact partials -> bf16 G (lower tiles), AND
// write the strict-upper mirror (transposed strip via LDS).
// ---------------------------------------------------------------------------
__global__ __launch_bounds__(256)
void reduce_cast_tri(const unsigned short* __restrict__ part,
                     unsigned short* __restrict__ outG, int split)
{
    __shared__ unsigned short s[8][132];
    const long DD = (long)DIM * DIM;
    int id = blockIdx.x * 256 + threadIdx.x;
    const int b  = id / 147456;          // 36*128*32
    int rem      = id % 147456;
    const int tlin = rem / 4096;
    const int rr = rem % 4096;
    const int r  = rr >> 5;
    const int c4 = rr & 31;
    int t = tlin, ti = 0;
    while (t > ti) { t -= ti + 1; ++ti; }
    const long off = (long)tlin * 16384 + r * 128 + c4 * 4;

    float4 sum = make_float4(0.f, 0.f, 0.f, 0.f);
    for (int sp = 0; sp < split; ++sp) {
        ushort4 v = *(const ushort4*)&part[(long)(b * split + sp) * TRI_SLICE + off];
        sum.x += bf2f(v.x); sum.y += bf2f(v.y); sum.z += bf2f(v.z); sum.w += bf2f(v.w);
    }
    ushort4 o;
    o.x = f2bf(sum.x); o.y = f2bf(sum.y); o.z = f2bf(sum.z); o.w = f2bf(sum.w);
    *(ushort4*)&outG[b * DD + ((long)ti * 128 + r) * DIM + (long)t * 128 + c4 * 4] = o;

    if (t == ti) return;                 // diagonal tile: already complete

    const int rl = r & 7;
    s[rl][c4 * 4 + 0] = o.x; s[rl][c4 * 4 + 1] = o.y;
    s[rl][c4 * 4 + 2] = o.z; s[rl][c4 * 4 + 3] = o.w;
    __syncthreads();

    const int r0 = r & ~7;
    const int co = threadIdx.x >> 1;
    const int hf = threadIdx.x & 1;
    ushort4 m;
    m.x = s[hf * 4 + 0][co]; m.y = s[hf * 4 + 1][co];
    m.z = s[hf * 4 + 2][co]; m.w = s[hf * 4 + 3][co];
    *(ushort4*)&outG[b * DD + ((long)t * 128 + co) * DIM
                     + (long)ti * 128 + r0 + hf * 4] = m;
}

// ---------------------------------------------------------------------------
// Unified prep, 4x ILP: each block covers a 32-row x 128-col strip.
// z < BATCH: x batch z -> xb + xTb.  z == BATCH: weights cast / P transpose.
// Grid (DIM/128, SEQ/32, BATCH+1).
// ---------------------------------------------------------------------------
__global__ __launch_bounds__(256)
void prep_all(const float* __restrict__ x,
              const float* __restrict__ Wq, const float* __restrict__ Wk,
              const float* __restrict__ Wv, const float* __restrict__ P,
              unsigned short* __restrict__ xb, unsigned short* __restrict__ xTb,
              unsigned short* __restrict__ Wqb, unsigned short* __restrict__ Wkb,
              unsigned short* __restrict__ Wvb, unsigned short* __restrict__ Ptb)
{
    __shared__ unsigned short t[4][32][33];
    const int z = blockIdx.z;
    const int row = threadIdx.x >> 3;
    const int cid = threadIdx.x & 7;

    if (z < BATCH) {
        const long base = (long)z * SEQ * DIM;
        const int r0 = blockIdx.y * 32;      // over S
        const int c0 = blockIdx.x * 128;     // over D
        ushort4 h[4];
#pragma unroll
        for (int i = 0; i < 4; ++i) {
            float4 v = *(const float4*)&x[base + (long)(r0 + row) * DIM
                                          + c0 + i * 32 + cid * 4];
            h[i].x = f2bf(v.x); h[i].y = f2bf(v.y);
            h[i].z = f2bf(v.z); h[i].w = f2bf(v.w);
        }
#pragma unroll
        for (int i = 0; i < 4; ++i) {
            *(ushort4*)&xb[base + (long)(r0 + row) * DIM + c0 + i * 32 + cid * 4] = h[i];
            t[i][row][cid * 4 + 0] = h[i].x; t[i][row][cid * 4 + 1] = h[i].y;
            t[i][row][cid * 4 + 2] = h[i].z; t[i][row][cid * 4 + 3] = h[i].w;
        }
        __syncthreads();
#pragma unroll
        for (int i = 0; i < 4; ++i) {
            ushort4 o;
            o.x = t[i][cid * 4 + 0][row];
            o.y = t[i][cid * 4 + 1][row];
            o.z = t[i][cid * 4 + 2][row];
            o.w = t[i][cid * 4 + 3][row];
            *(ushort4*)&xTb[base + (long)(c0 + i * 32 + row) * SEQ + r0 + cid * 4] = o;
        }
        return;
    }

    const int wsel = blockIdx.y >> 5;        // 0=Wq 1=Wk 2=Wv 3=P
    const int r0 = (blockIdx.y & 31) * 32;
    const int c0 = blockIdx.x * 128;
    const float* src = (wsel == 0) ? Wq : (wsel == 1) ? Wk : (wsel == 2) ? Wv : P;

    ushort4 h[4];
#pragma unroll
    for (int i = 0; i < 4; ++i) {
        float4 v = *(const float4*)&src[(long)(r0 + row) * DIM + c0 + i * 32 + cid * 4];
        h[i].x = f2bf(v.x); h[i].y = f2bf(v.y);
        h[i].z = f2bf(v.z); h[i].w = f2bf(v.w);
    }

    if (wsel < 3) {
        unsigned short* dst = (wsel == 0) ? Wqb : (wsel == 1) ? Wkb : Wvb;
#pragma unroll
        for (int i = 0; i < 4; ++i)
            *(ushort4*)&dst[(long)(r0 + row) * DIM + c0 + i * 32 + cid * 4] = h[i];
        return;
    }
#pragma unroll
    for (int i = 0; i < 4; ++i) {
        t[i][row][cid * 4 + 0] = h[i].x; t[i][row][cid * 4 + 1] = h[i].y;
        t[i][row][cid * 4 + 2] = h[i].z; t[i][row][cid * 4 + 3] = h[i].w;
    }
    __syncthreads();
#pragma unroll
    for (int i = 0; i < 4; ++i) {
        ushort4 o;
        o.x = t[i][cid * 4 + 0][row];
        o.y = t[i][cid * 4 + 1][row];
        o.z = t[i][cid * 4 + 2][row];
        o.w = t[i][cid * 4 + 3][row];
        *(ushort4*)&Ptb[(long)(c0 + i * 32 + row) * DIM + r0 + cid * 4] = o;
    }
}

// ---------------------------------------------------------------------------
extern "C" void kernel_launch(void* const* d_in, const int* in_sizes, int n_in,
                              void* d_out, int out_size, void* d_ws, size_t ws_size,
                              hipStream_t stream)
{
    const float* x  = (const float*)d_in[0];
    const float* Wq = (const float*)d_in[1];
    const float* Wk = (const float*)d_in[2];
    const float* Wv = (const float*)d_in[3];
    const float* P  = (const float*)d_in[4];
    float* out = (float*)d_out;

    const long DD = (long)DIM * DIM;
    const long SD = (long)SEQ * DIM;

    // workspace layout (MiB offsets) — proven map; regA bf16 (18 MiB @ split=4):
    //   [0,32) xb | [32,64) xTb -> Hb[32,40) Ntb[40,48)
    //   [64,72) Gb | [72,84) weights | [84,102) regA gram bf16 partials
    uint8_t* ws = (uint8_t*)d_ws;
    unsigned short* xb   = (unsigned short*)(ws);
    unsigned short* xTb  = (unsigned short*)(ws + (32ul << 20));
    unsigned short* Hb   = (unsigned short*)(ws + (32ul << 20));
    unsigned short* Ntb  = (unsigned short*)(ws + (40ul << 20));
    unsigned short* Gb   = (unsigned short*)(ws + (64ul << 20));
    unsigned short* Wqb  = (unsigned short*)(ws + (72ul << 20));
    unsigned short* Ptb  = (unsigned short*)(ws + (74ul << 20));
    unsigned short* Wkb  = (unsigned short*)(ws + (76ul << 20));
    unsigned short* Wvb  = (unsigned short*)(ws + (78ul << 20));
    unsigned short* Ub   = (unsigned short*)(ws + (80ul << 20));
    unsigned short* W2Tb = (unsigned short*)(ws + (82ul << 20));
    unsigned short* regA = (unsigned short*)(ws + (84ul << 20));

    const int split = 4;                 // nt=16 gram blocks == weights blocks
    const int NG = 36 * split * BATCH;   // 576 gram blocks

    // 1) x -> xb, xTb ; Wq/Wk/Wv -> bf16 ; P -> Pt   (single launch, 4x ILP)
    prep_all<<<dim3(DIM / 128, SEQ / 32, BATCH + 1), 256, 0, stream>>>(
        x, Wq, Wk, Wv, P, xb, xTb, Wqb, Wkb, Wvb, Ptb);

    // 2) merged: gram lower-tile bf16 partials + weights GEMMs {U, W2T}
    //    (576 + 128 = 704 blocks, ALL nt=16)
    gram_w<<<dim3(NG + 128), 256, 0, stream>>>(
        xTb, regA, Wqb, Wkb, Ptb, Wvb, Ub, W2Tb, SEQ / split, split, NG);
    reduce_cast_tri<<<dim3(BATCH * 36 * 128 * 32 / 256), 256, 0, stream>>>(
        regA, Gb, split);

    // 3) H_b = U @ G_b^T  (G symmetric)
    gemm_db<false><<<dim3(16, 8, BATCH), 256, 0, stream>>>(
        Ub, Gb, Hb, DIM, 1, DIM, DIM, DIM, 0, DD, DD);

    // 4) Nt_b = W2T @ H_b^T + I   (residual folded in)
    gemm_db<true><<<dim3(16, 8, BATCH), 256, 0, stream>>>(
        W2Tb, Hb, Ntb, DIM, 1, DIM, DIM, DIM, 0, DD, DD);

    // 5) out_b = xb_b @ Nt_b^T  (fp32 out, 256x256 2-cluster pipeline)
    gemm_db256<<<dim3(DIM / 256, SEQ / 256, BATCH), 512, 0, stream>>>(
        xb, Ntb, out, DIM, DIM, DIM, DIM, SD, DD, SD);
}

// Round 23
// 135.052 us; speedup vs baseline: 1.4720x; 1.0256x over previous
//
#include <hip/hip_runtime.h>
#include <hip/hip_bf16.h>
#include <stdint.h>

// out = x + x * [ (Wq Wk^T) * (x^T x) * (Wv P) ]  ==  x @ (I + N),  N = U G W2
// Final GEMM: 256x256 8-wave 2-cluster counted-vmcnt pipeline (best measured).
// Merged gram+weights launch with split=2 -> 288 gram (nt=32) + 128 weights
// (nt=16) = 416 blocks, ALL co-resident (capacity 512): same makespan as
// split=4 but half the prologue/drain events and half the partial traffic.
// Prep: 4x-ILP strip version. Reduce: fused symmetric mirror.

#define BATCH 4
#define SEQ   4096
#define DIM   1024

#define TRI_SLICE 589824l       // 36 tiles * 128*128 elements per gram slice

typedef __bf16 bf16x8 __attribute__((ext_vector_type(8)));
typedef float f32x4 __attribute__((ext_vector_type(4)));

static __device__ __forceinline__ unsigned short f2bf(float f) {
    unsigned int u = __builtin_bit_cast(unsigned int, f);
    u += 0x7fff + ((u >> 16) & 1);              // RNE
    return (unsigned short)(u >> 16);
}
static __device__ __forceinline__ float bf2f(unsigned short h) {
    unsigned int u = (unsigned int)h << 16;
    return __builtin_bit_cast(float, u);
}

// ---------------------------------------------------------------------------
// 256x256-tile deep-pipelined bf16 MFMA GEMM: C = A @ Bt^T (fp32 out).
//  512 threads = 8 waves (2M x 4N), per-wave 128x64 output.
//  LDS [2][256][64] x2 = 128 KiB (1 block/CU). vmcnt(8) counted protocol.
//  Grid: (N/256, M/256, BATCH); flattened nwg % 8 == 0. K/64 >= 2.
// ---------------------------------------------------------------------------
__global__ __launch_bounds__(512)
void gemm_db256(const unsigned short* __restrict__ Ag,
                const unsigned short* __restrict__ Btg,
                float* __restrict__ Cg,
                int K, int lda, int ldbt, int ldc,
                long sA, long sBt, long sC)
{
    __shared__ unsigned short As[2][256][64];
    __shared__ unsigned short Bs[2][256][64];

    const int gx = gridDim.x, gy = gridDim.y;
    const int nwg = gx * gy * gridDim.z;
    int id = blockIdx.x + gx * (blockIdx.y + gy * blockIdx.z);
    id = (id & 7) * (nwg >> 3) + (id >> 3);

    const int bx = id % gx;
    const int rest = id / gx;
    const int by = rest % gy;
    const int b = rest / gy;
    const long i0 = (long)by * 256;
    const long j0 = (long)bx * 256;

    const unsigned short* A  = Ag  + (long)b * sA;
    const unsigned short* Bt = Btg + (long)b * sBt;

    const int tid  = threadIdx.x;
    const int lane = tid & 63;
    const int w    = tid >> 6;          // wave 0..7
    const int wr   = w >> 2;            // 0..1  (M half)
    const int wc   = w & 3;             // 0..3  (N quarter)
    const int lrow = lane >> 3;         // 0..7
    const int lcol = lane & 7;          // 0..7 (16B granule)
    const int fr   = lane & 15;
    const int kg   = lane >> 4;         // 0..3
    const int scol = (lcol ^ lrow) * 8; // pre-swizzled global source chunk

    f32x4 acc[8][4] = {};

    const int nt = K / 64;

    auto stage = [&](int t, int buf) {
        const long kk = (long)t * 64;
#pragma unroll
        for (int inst = 0; inst < 4; ++inst) {
            const int row = w * 32 + inst * 8;
            const unsigned short* srcA = A + (i0 + row + lrow) * lda + kk + scol;
            __builtin_amdgcn_global_load_lds(
                (const __attribute__((address_space(1))) void*)srcA,
                (__attribute__((address_space(3))) void*)&As[buf][row][0], 16, 0, 0);
            const unsigned short* srcB = Bt + (j0 + row + lrow) * ldbt + kk + scol;
            __builtin_amdgcn_global_load_lds(
                (const __attribute__((address_space(1))) void*)srcB,
                (__attribute__((address_space(3))) void*)&Bs[buf][row][0], 16, 0, 0);
        }
    };

    stage(0, 0);
    stage(1, 1);

    for (int t = 0; t < nt; ++t) {
        const int buf = t & 1;
        if (t < nt - 1) asm volatile("s_waitcnt vmcnt(8)" ::: "memory");
        else            asm volatile("s_waitcnt vmcnt(0)" ::: "memory");
        __builtin_amdgcn_s_barrier();
        asm volatile("" ::: "memory");

        // ---- cluster 0: reads (12 x b128) + MFMA (32)
        const int ch0 = (kg ^ (fr & 7)) * 8;
        bf16x8 af0[8], bf0[4];
#pragma unroll
        for (int m = 0; m < 8; ++m)
            af0[m] = *(const bf16x8*)&As[buf][wr * 128 + m * 16 + fr][ch0];
#pragma unroll
        for (int n = 0; n < 4; ++n)
            bf0[n] = *(const bf16x8*)&Bs[buf][wc * 64 + n * 16 + fr][ch0];
        __builtin_amdgcn_s_setprio(1);
#pragma unroll
        for (int m = 0; m < 8; ++m)
#pragma unroll
            for (int n = 0; n < 4; ++n)
                acc[m][n] = __builtin_amdgcn_mfma_f32_16x16x32_bf16(
                    af0[m], bf0[n], acc[m][n], 0, 0, 0);
        __builtin_amdgcn_s_setprio(0);

        // ---- cluster 1 reads
        const int ch1 = ((4 + kg) ^ (fr & 7)) * 8;
        bf16x8 af1[8], bf1[4];
#pragma unroll
        for (int m = 0; m < 8; ++m)
            af1[m] = *(const bf16x8*)&As[buf][wr * 128 + m * 16 + fr][ch1];
#pragma unroll
        for (int n = 0; n < 4; ++n)
            bf1[n] = *(const bf16x8*)&Bs[buf][wc * 64 + n * 16 + fr][ch1];

        asm volatile("s_waitcnt lgkmcnt(0)" ::: "memory");
        __builtin_amdgcn_sched_barrier(0);
        __builtin_amdgcn_s_barrier();          // all waves done reading buf
        asm volatile("" ::: "memory");

        if (t + 2 < nt) stage(t + 2, buf);     // loads fly under MFMA cluster 1
        __builtin_amdgcn_sched_barrier(0);

        __builtin_amdgcn_s_setprio(1);
#pragma unroll
        for (int m = 0; m < 8; ++m)
#pragma unroll
            for (int n = 0; n < 4; ++n)
                acc[m][n] = __builtin_amdgcn_mfma_f32_16x16x32_bf16(
                    af1[m], bf1[n], acc[m][n], 0, 0, 0);
        __builtin_amdgcn_s_setprio(0);
    }

    // ---- epilogue: C/D layout col = lane&15, row = (lane>>4)*4 + q
    float* C32 = Cg + (long)b * sC;
#pragma unroll
    for (int m = 0; m < 8; ++m) {
        const long rbase = i0 + wr * 128 + m * 16 + kg * 4;
#pragma unroll
        for (int n = 0; n < 4; ++n) {
            const long col = j0 + wc * 64 + n * 16 + fr;
#pragma unroll
            for (int q = 0; q < 4; ++q)
                C32[(rbase + q) * ldc + col] = acc[m][n][q];
        }
    }
}

// ---------------------------------------------------------------------------
// Merged gram + weights launch (1-D grid = NG + 128, NG = 36*split*BATCH):
//  id <  NG : gram slice — lower-triangle tile, K=K1, compact bf16 partial.
//  id >= NG : weights GEMM — wid>>6 selects {U = Wq@Wk^T ; W2T = Pt@Wv^T},
//             64 tiles each (128x128), K=DIM, bf16 out.
//  split=2: 288 gram blocks (nt=32) + 128 weights (nt=16) = 416 blocks,
//  all co-resident at 2 blocks/CU.
// ---------------------------------------------------------------------------
__global__ __launch_bounds__(256)
void gram_w(const unsigned short* __restrict__ xT,
            unsigned short* __restrict__ part,
            const unsigned short* __restrict__ Wqb,
            const unsigned short* __restrict__ Wkb,
            const unsigned short* __restrict__ Ptb,
            const unsigned short* __restrict__ Wvb,
            unsigned short* __restrict__ Ub,
            unsigned short* __restrict__ W2Tb,
            int K1, int split, int NG)
{
    __shared__ unsigned short As[2][128][64];
    __shared__ unsigned short Bs[2][128][64];

    const long SD = (long)SEQ * DIM;
    const int nwg = gridDim.x;
    int id = blockIdx.x;
    id = (id & 7) * (nwg >> 3) + (id >> 3);

    const unsigned short *A, *Bt;
    unsigned short* C16 = nullptr;       // weights bf16 out
    unsigned short* Cp  = nullptr;       // gram compact partial out
    long i0, j0, lda, ldbt;
    int nt;

    if (id < NG) {
        const int z = id / 36;
        const int tlin = id % 36;
        int t = tlin, ti = 0;
        while (t > ti) { t -= ti + 1; ++ti; }
        i0 = (long)ti * 128;
        j0 = (long)t * 128;
        const int b = z / split;
        const long koff = (long)(z % split) * K1;
        A  = xT + (long)b * SD + koff;
        Bt = A;
        lda = ldbt = SEQ;
        nt = K1 / 64;
        Cp = part + (long)z * TRI_SLICE + (long)tlin * 16384;
    } else {
        const int wid = id - NG;
        const int z2 = wid >> 6;         // 0 = U, 1 = W2T
        const int t = wid & 63;
        i0 = (long)(t >> 3) * 128;
        j0 = (long)(t & 7) * 128;
        A   = z2 ? Ptb : Wqb;
        Bt  = z2 ? Wvb : Wkb;
        C16 = z2 ? W2Tb : Ub;
        lda = ldbt = DIM;
        nt = DIM / 64;                   // 16
    }

    const int tid  = threadIdx.x;
    const int lane = tid & 63;
    const int w    = tid >> 6;          // wave 0..3
    const int wr   = w >> 1, wc = w & 1;
    const int lrow = lane >> 3;         // 0..7
    const int lcol = lane & 7;          // 0..7 (16B granule)
    const int fr   = lane & 15;
    const int kg   = lane >> 4;         // 0..3
    const int scol = (lcol ^ lrow) * 8; // pre-swizzled global source chunk

    f32x4 acc[4][4] = {};

    auto stage = [&](int t, int buf) {
        const long kk = (long)t * 64;
#pragma unroll
        for (int inst = 0; inst < 4; ++inst) {
            const int row = w * 32 + inst * 8;
            const unsigned short* srcA = A + (i0 + row + lrow) * lda + kk + scol;
            __builtin_amdgcn_global_load_lds(
                (const __attribute__((address_space(1))) void*)srcA,
                (__attribute__((address_space(3))) void*)&As[buf][row][0], 16, 0, 0);
            const unsigned short* srcB = Bt + (j0 + row + lrow) * ldbt + kk + scol;
            __builtin_amdgcn_global_load_lds(
                (const __attribute__((address_space(1))) void*)srcB,
                (__attribute__((address_space(3))) void*)&Bs[buf][row][0], 16, 0, 0);
        }
    };

    stage(0, 0);
    stage(1, 1);

    for (int t = 0; t < nt; ++t) {
        const int buf = t & 1;
        if (t < nt - 1) asm volatile("s_waitcnt vmcnt(8)" ::: "memory");
        else            asm volatile("s_waitcnt vmcnt(0)" ::: "memory");
        __builtin_amdgcn_s_barrier();
        asm volatile("" ::: "memory");

        bf16x8 af0[4], bf0[4], af1[4], bf1[4];
        const int ch0 = (kg ^ (fr & 7)) * 8;
        const int ch1 = ((4 + kg) ^ (fr & 7)) * 8;
#pragma unroll
        for (int m = 0; m < 4; ++m)
            af0[m] = *(const bf16x8*)&As[buf][wr * 64 + m * 16 + fr][ch0];
#pragma unroll
        for (int n = 0; n < 4; ++n)
            bf0[n] = *(const bf16x8*)&Bs[buf][wc * 64 + n * 16 + fr][ch0];
#pragma unroll
        for (int m = 0; m < 4; ++m)
            af1[m] = *(const bf16x8*)&As[buf][wr * 64 + m * 16 + fr][ch1];
#pragma unroll
        for (int n = 0; n < 4; ++n)
            bf1[n] = *(const bf16x8*)&Bs[buf][wc * 64 + n * 16 + fr][ch1];

        __builtin_amdgcn_s_setprio(1);
#pragma unroll
        for (int m = 0; m < 4; ++m)
#pragma unroll
            for (int n = 0; n < 4; ++n)
                acc[m][n] = __builtin_amdgcn_mfma_f32_16x16x32_bf16(
                    af0[m], bf0[n], acc[m][n], 0, 0, 0);
        __builtin_amdgcn_s_setprio(0);

        asm volatile("s_waitcnt lgkmcnt(0)" ::: "memory");
        __builtin_amdgcn_sched_barrier(0);
        __builtin_amdgcn_s_barrier();
        asm volatile("" ::: "memory");

        if (t + 2 < nt) stage(t + 2, buf);
        __builtin_amdgcn_sched_barrier(0);

        __builtin_amdgcn_s_setprio(1);
#pragma unroll
        for (int m = 0; m < 4; ++m)
#pragma unroll
            for (int n = 0; n < 4; ++n)
                acc[m][n] = __builtin_amdgcn_mfma_f32_16x16x32_bf16(
                    af1[m], bf1[n], acc[m][n], 0, 0, 0);
        __builtin_amdgcn_s_setprio(0);
    }

    // epilogue: C/D layout col = lane&15, row = (lane>>4)*4 + q
    if (Cp) {
#pragma unroll
        for (int m = 0; m < 4; ++m) {
            const int lrb = wr * 64 + m * 16 + kg * 4;
#pragma unroll
            for (int n = 0; n < 4; ++n) {
                const int lc = wc * 64 + n * 16 + fr;
#pragma unroll
                for (int q = 0; q < 4; ++q)
                    Cp[(lrb + q) * 128 + lc] = f2bf(acc[m][n][q]);
            }
        }
        return;
    }
#pragma unroll
    for (int m = 0; m < 4; ++m) {
        const long rbase = i0 + wr * 64 + m * 16 + kg * 4;
#pragma unroll
        for (int n = 0; n < 4; ++n) {
            const long col = j0 + wc * 64 + n * 16 + fr;
#pragma unroll
            for (int q = 0; q < 4; ++q)
                C16[(rbase + q) * DIM + col] = f2bf(acc[m][n][q]);
        }
    }
}

// ---------------------------------------------------------------------------
// 128 x 64 deep-pipelined bf16 MFMA GEMM — D x D chain (H, Nt).
//  bf16 out (+ optional identity add).
// ---------------------------------------------------------------------------
template<bool ADD_I>
__global__ __launch_bounds__(256)
void gemm_db(const unsigned short* __restrict__ Ag,
             const unsigned short* __restrict__ Btg,
             void* __restrict__ Cg,
             int K, int zdiv, int lda, int ldbt, int ldc,
             long sA, long sBt, long sC)
{
    constexpr int BN = 64, NF = 2;
    __shared__ unsigned short As[2][128][64];
    __shared__ unsigned short Bs[2][BN][64];

    const int gx = gridDim.x, gy = gridDim.y;
    const int nwg = gx * gy * gridDim.z;
    int id = blockIdx.x + gx * (blockIdx.y + gy * blockIdx.z);
    id = (id & 7) * (nwg >> 3) + (id >> 3);

    const int bx = id % gx;
    const int rest = id / gx;
    const int by = rest % gy;
    const int z = rest / gy;
    const long i0 = (long)by * 128;
    const long j0 = (long)bx * BN;
    const int b = z / zdiv;
    const long koff = (long)(z % zdiv) * K;

    const unsigned short* A  = Ag  + (long)b * sA  + koff;
    const unsigned short* Bt = Btg + (long)b * sBt + koff;

    const int tid  = threadIdx.x;
    const int lane = tid & 63;
    const int w    = tid >> 6;          // wave 0..3
    const int wr   = w >> 1, wc = w & 1;
    const int lrow = lane >> 3;
    const int lcol = lane & 7;
    const int fr   = lane & 15;
    const int kg   = lane >> 4;
    const int scol = (lcol ^ lrow) * 8;

    f32x4 acc[4][NF] = {};

    const int nt = K / 64;

    auto stage = [&](int t, int buf) {
        const long kk = (long)t * 64;
#pragma unroll
        for (int inst = 0; inst < 4; ++inst) {
            const int row = w * 32 + inst * 8;
            const unsigned short* srcA = A + (i0 + row + lrow) * lda + kk + scol;
            __builtin_amdgcn_global_load_lds(
                (const __attribute__((address_space(1))) void*)srcA,
                (__attribute__((address_space(3))) void*)&As[buf][row][0], 16, 0, 0);
        }
#pragma unroll
        for (int inst = 0; inst < NF; ++inst) {
            const int row = w * (8 * NF) + inst * 8;
            const unsigned short* srcB = Bt + (j0 + row + lrow) * ldbt + kk + scol;
            __builtin_amdgcn_global_load_lds(
                (const __attribute__((address_space(1))) void*)srcB,
                (__attribute__((address_space(3))) void*)&Bs[buf][row][0], 16, 0, 0);
        }
    };

    stage(0, 0);
    stage(1, 1);

    for (int t = 0; t < nt; ++t) {
        const int buf = t & 1;
        if (t < nt - 1) asm volatile("s_waitcnt vmcnt(6)" ::: "memory");
        else            asm volatile("s_waitcnt vmcnt(0)" ::: "memory");
        __builtin_amdgcn_s_barrier();
        asm volatile("" ::: "memory");

        bf16x8 af0[4], bf0[NF], af1[4], bf1[NF];
        const int ch0 = (kg ^ (fr & 7)) * 8;
        const int ch1 = ((4 + kg) ^ (fr & 7)) * 8;
#pragma unroll
        for (int m = 0; m < 4; ++m)
            af0[m] = *(const bf16x8*)&As[buf][wr * 64 + m * 16 + fr][ch0];
#pragma unroll
        for (int n = 0; n < NF; ++n)
            bf0[n] = *(const bf16x8*)&Bs[buf][wc * (BN / 2) + n * 16 + fr][ch0];
#pragma unroll
        for (int m = 0; m < 4; ++m)
            af1[m] = *(const bf16x8*)&As[buf][wr * 64 + m * 16 + fr][ch1];
#pragma unroll
        for (int n = 0; n < NF; ++n)
            bf1[n] = *(const bf16x8*)&Bs[buf][wc * (BN / 2) + n * 16 + fr][ch1];

        __builtin_amdgcn_s_setprio(1);
#pragma unroll
        for (int m = 0; m < 4; ++m)
#pragma unroll
            for (int n = 0; n < NF; ++n)
                acc[m][n] = __builtin_amdgcn_mfma_f32_16x16x32_bf16(
                    af0[m], bf0[n], acc[m][n], 0, 0, 0);
        __builtin_amdgcn_s_setprio(0);

        asm volatile("s_waitcnt lgkmcnt(0)" ::: "memory");
        __builtin_amdgcn_sched_barrier(0);
        __builtin_amdgcn_s_barrier();
        asm volatile("" ::: "memory");

        if (t + 2 < nt) stage(t + 2, buf);
        __builtin_amdgcn_sched_barrier(0);

        __builtin_amdgcn_s_setprio(1);
#pragma unroll
        for (int m = 0; m < 4; ++m)
#pragma unroll
            for (int n = 0; n < NF; ++n)
                acc[m][n] = __builtin_amdgcn_mfma_f32_16x16x32_bf16(
                    af1[m], bf1[n], acc[m][n], 0, 0, 0);
        __builtin_amdgcn_s_setprio(0);
    }

    unsigned short* C16 = (unsigned short*)Cg + (long)b * sC;
#pragma unroll
    for (int m = 0; m < 4; ++m) {
        const long rbase = i0 + wr * 64 + m * 16 + kg * 4;
#pragma unroll
        for (int n = 0; n < NF; ++n) {
            const long col = j0 + wc * (BN / 2) + n * 16 + fr;
#pragma unroll
            for (int q = 0; q < 4; ++q) {
                const long r = rbase + q;
                float v = acc[m][n][q];
                if (ADD_I && r == col) v += 1.0f;
                C16[r * ldc + col] = f2bf(v);
            }
        }
    }
}

// ---------------------------------------------------------------------------
// Reduce gram split-K BF16 compact partials -> bf16 G (lower tiles), AND
// write the strict-upper mirror (transposed strip via LDS).
// ---------------------------------------------------------------------------
__global__ __launch_bounds__(256)
void reduce_cast_tri(const unsigned short* __restrict__ part,
                     unsigned short* __restrict__ outG, int split)
{
    __shared__ unsigned short s[8][132];
    const long DD = (long)DIM * DIM;
    int id = blockIdx.x * 256 + threadIdx.x;
    const int b  = id / 147456;          // 36*128*32
    int rem      = id % 147456;
    const int tlin = rem / 4096;
    const int rr = rem % 4096;
    const int r  = rr >> 5;
    const int c4 = rr & 31;
    int t = tlin, ti = 0;
    while (t > ti) { t -= ti + 1; ++ti; }
    const long off = (long)tlin * 16384 + r * 128 + c4 * 4;

    float4 sum = make_float4(0.f, 0.f, 0.f, 0.f);
    for (int sp = 0; sp < split; ++sp) {
        ushort4 v = *(const ushort4*)&part[(long)(b * split + sp) * TRI_SLICE + off];
        sum.x += bf2f(v.x); sum.y += bf2f(v.y); sum.z += bf2f(v.z); sum.w += bf2f(v.w);
    }
    ushort4 o;
    o.x = f2bf(sum.x); o.y = f2bf(sum.y); o.z = f2bf(sum.z); o.w = f2bf(sum.w);
    *(ushort4*)&outG[b * DD + ((long)ti * 128 + r) * DIM + (long)t * 128 + c4 * 4] = o;

    if (t == ti) return;                 // diagonal tile: already complete

    const int rl = r & 7;
    s[rl][c4 * 4 + 0] = o.x; s[rl][c4 * 4 + 1] = o.y;
    s[rl][c4 * 4 + 2] = o.z; s[rl][c4 * 4 + 3] = o.w;
    __syncthreads();

    const int r0 = r & ~7;
    const int co = threadIdx.x >> 1;
    const int hf = threadIdx.x & 1;
    ushort4 m;
    m.x = s[hf * 4 + 0][co]; m.y = s[hf * 4 + 1][co];
    m.z = s[hf * 4 + 2][co]; m.w = s[hf * 4 + 3][co];
    *(ushort4*)&outG[b * DD + ((long)t * 128 + co) * DIM
                     + (long)ti * 128 + r0 + hf * 4] = m;
}

// ---------------------------------------------------------------------------
// Unified prep, 4x ILP: each block covers a 32-row x 128-col strip.
// z < BATCH: x batch z -> xb + xTb.  z == BATCH: weights cast / P transpose.
// Grid (DIM/128, SEQ/32, BATCH+1).
// ---------------------------------------------------------------------------
__global__ __launch_bounds__(256)
void prep_all(const float* __restrict__ x,
              const float* __restrict__ Wq, const float* __restrict__ Wk,
              const float* __restrict__ Wv, const float* __restrict__ P,
              unsigned short* __restrict__ xb, unsigned short* __restrict__ xTb,
              unsigned short* __restrict__ Wqb, unsigned short* __restrict__ Wkb,
              unsigned short* __restrict__ Wvb, unsigned short* __restrict__ Ptb)
{
    __shared__ unsigned short t[4][32][33];
    const int z = blockIdx.z;
    const int row = threadIdx.x >> 3;
    const int cid = threadIdx.x & 7;

    if (z < BATCH) {
        const long base = (long)z * SEQ * DIM;
        const int r0 = blockIdx.y * 32;      // over S
        const int c0 = blockIdx.x * 128;     // over D
        ushort4 h[4];
#pragma unroll
        for (int i = 0; i < 4; ++i) {
            float4 v = *(const float4*)&x[base + (long)(r0 + row) * DIM
                                          + c0 + i * 32 + cid * 4];
            h[i].x = f2bf(v.x); h[i].y = f2bf(v.y);
            h[i].z = f2bf(v.z); h[i].w = f2bf(v.w);
        }
#pragma unroll
        for (int i = 0; i < 4; ++i) {
            *(ushort4*)&xb[base + (long)(r0 + row) * DIM + c0 + i * 32 + cid * 4] = h[i];
            t[i][row][cid * 4 + 0] = h[i].x; t[i][row][cid * 4 + 1] = h[i].y;
            t[i][row][cid * 4 + 2] = h[i].z; t[i][row][cid * 4 + 3] = h[i].w;
        }
        __syncthreads();
#pragma unroll
        for (int i = 0; i < 4; ++i) {
            ushort4 o;
            o.x = t[i][cid * 4 + 0][row];
            o.y = t[i][cid * 4 + 1][row];
            o.z = t[i][cid * 4 + 2][row];
            o.w = t[i][cid * 4 + 3][row];
            *(ushort4*)&xTb[base + (long)(c0 + i * 32 + row) * SEQ + r0 + cid * 4] = o;
        }
        return;
    }

    const int wsel = blockIdx.y >> 5;        // 0=Wq 1=Wk 2=Wv 3=P
    const int r0 = (blockIdx.y & 31) * 32;
    const int c0 = blockIdx.x * 128;
    const float* src = (wsel == 0) ? Wq : (wsel == 1) ? Wk : (wsel == 2) ? Wv : P;

    ushort4 h[4];
#pragma unroll
    for (int i = 0; i < 4; ++i) {
        float4 v = *(const float4*)&src[(long)(r0 + row) * DIM + c0 + i * 32 + cid * 4];
        h[i].x = f2bf(v.x); h[i].y = f2bf(v.y);
        h[i].z = f2bf(v.z); h[i].w = f2bf(v.w);
    }

    if (wsel < 3) {
        unsigned short* dst = (wsel == 0) ? Wqb : (wsel == 1) ? Wkb : Wvb;
#pragma unroll
        for (int i = 0; i < 4; ++i)
            *(ushort4*)&dst[(long)(r0 + row) * DIM + c0 + i * 32 + cid * 4] = h[i];
        return;
    }
#pragma unroll
    for (int i = 0; i < 4; ++i) {
        t[i][row][cid * 4 + 0] = h[i].x; t[i][row][cid * 4 + 1] = h[i].y;
        t[i][row][cid * 4 + 2] = h[i].z; t[i][row][cid * 4 + 3] = h[i].w;
    }
    __syncthreads();
#pragma unroll
    for (int i = 0; i < 4; ++i) {
        ushort4 o;
        o.x = t[i][cid * 4 + 0][row];
        o.y = t[i][cid * 4 + 1][row];
        o.z = t[i][cid * 4 + 2][row];
        o.w = t[i][cid * 4 + 3][row];
        *(ushort4*)&Ptb[(long)(c0 + i * 32 + row) * DIM + r0 + cid * 4] = o;
    }
}

// ---------------------------------------------------------------------------
extern "C" void kernel_launch(void* const* d_in, const int* in_sizes, int n_in,
                              void* d_out, int out_size, void* d_ws, size_t ws_size,
                              hipStream_t stream)
{
    const float* x  = (const float*)d_in[0];
    const float* Wq = (const float*)d_in[1];
    const float* Wk = (const float*)d_in[2];
    const float* Wv = (const float*)d_in[3];
    const float* P  = (const float*)d_in[4];
    float* out = (float*)d_out;

    const long DD = (long)DIM * DIM;
    const long SD = (long)SEQ * DIM;

    // workspace layout (MiB offsets) — proven map; regA bf16 (9 MiB @ split=2):
    //   [0,32) xb | [32,64) xTb -> Hb[32,40) Ntb[40,48)
    //   [64,72) Gb | [72,84) weights | [84,93) regA gram bf16 partials
    uint8_t* ws = (uint8_t*)d_ws;
    unsigned short* xb   = (unsigned short*)(ws);
    unsigned short* xTb  = (unsigned short*)(ws + (32ul << 20));
    unsigned short* Hb   = (unsigned short*)(ws + (32ul << 20));
    unsigned short* Ntb  = (unsigned short*)(ws + (40ul << 20));
    unsigned short* Gb   = (unsigned short*)(ws + (64ul << 20));
    unsigned short* Wqb  = (unsigned short*)(ws + (72ul << 20));
    unsigned short* Ptb  = (unsigned short*)(ws + (74ul << 20));
    unsigned short* Wkb  = (unsigned short*)(ws + (76ul << 20));
    unsigned short* Wvb  = (unsigned short*)(ws + (78ul << 20));
    unsigned short* Ub   = (unsigned short*)(ws + (80ul << 20));
    unsigned short* W2Tb = (unsigned short*)(ws + (82ul << 20));
    unsigned short* regA = (unsigned short*)(ws + (84ul << 20));

    const int split = 2;                 // 288 gram blocks (nt=32)
    const int NG = 36 * split * BATCH;   // 288

    // 1) x -> xb, xTb ; Wq/Wk/Wv -> bf16 ; P -> Pt   (single launch, 4x ILP)
    prep_all<<<dim3(DIM / 128, SEQ / 32, BATCH + 1), 256, 0, stream>>>(
        x, Wq, Wk, Wv, P, xb, xTb, Wqb, Wkb, Wvb, Ptb);

    // 2) merged: gram lower-tile bf16 partials + weights GEMMs {U, W2T}
    //    (288 + 128 = 416 blocks, all co-resident at 2 blocks/CU)
    gram_w<<<dim3(NG + 128), 256, 0, stream>>>(
        xTb, regA, Wqb, Wkb, Ptb, Wvb, Ub, W2Tb, SEQ / split, split, NG);
    reduce_cast_tri<<<dim3(BATCH * 36 * 128 * 32 / 256), 256, 0, stream>>>(
        regA, Gb, split);

    // 3) H_b = U @ G_b^T  (G symmetric)
    gemm_db<false><<<dim3(16, 8, BATCH), 256, 0, stream>>>(
        Ub, Gb, Hb, DIM, 1, DIM, DIM, DIM, 0, DD, DD);

    // 4) Nt_b = W2T @ H_b^T + I   (residual folded in)
    gemm_db<true><<<dim3(16, 8, BATCH), 256, 0, stream>>>(
        W2Tb, Hb, Ntb, DIM, 1, DIM, DIM, DIM, 0, DD, DD);

    // 5) out_b = xb_b @ Nt_b^T  (fp32 out, 256x256 2-cluster pipeline)
    gemm_db256<<<dim3(DIM / 256, SEQ / 256, BATCH), 512, 0, stream>>>(
        xb, Ntb, out, DIM, DIM, DIM, DIM, SD, DD, SD);
}